// Round 1
// baseline (441.161 us; speedup 1.0000x reference)
//
#include <hip/hip_runtime.h>
#include <stdint.h>

#define B_ 2
#define L_ 2048
#define DM 1024
#define NH 16
#define DH 64
#define M_ (B_*L_)   // 4096

typedef short short8 __attribute__((ext_vector_type(8)));
typedef float f32x4 __attribute__((ext_vector_type(4)));

__device__ __forceinline__ unsigned short f2b(float f) {
    union { float f; unsigned int u; } v; v.f = f;
    unsigned int u = v.u;
    unsigned int r = (u + 0x7fffu + ((u >> 16) & 1u)) >> 16;   // RNE
    return (unsigned short)r;
}
__device__ __forceinline__ float b2f(unsigned short h) {
    union { unsigned int u; float f; } v; v.u = ((unsigned int)h) << 16;
    return v.f;
}

// C[M][N] = A[M][K] * W[K][N] + bias.  A: fp32 or bf16 (row-major). W: fp32 row-major.
// Out: bf16 or fp32. 64x64 tile, BK=32, 256 threads (4 waves), MFMA 16x16x32 bf16.
template<bool A_BF16, bool OUT_BF16>
__global__ __launch_bounds__(256)
void gemm_bias_kernel(const void* __restrict__ Ain, const float* __restrict__ W,
                      const float* __restrict__ bias, void* __restrict__ Cout,
                      int M, int N, int K)
{
    // stride 40 elems (=80B): row-phase shifts banks by 20 words -> worst 2-way (free)
    __shared__ __align__(16) unsigned short Asl[64][40];  // A[m][k]
    __shared__ __align__(16) unsigned short Bsl[64][40];  // B^T: [n][k]

    const int t    = threadIdx.x;
    const int wave = t >> 6, lane = t & 63;
    const int quad = lane >> 4, l16 = lane & 15;
    const int m0 = blockIdx.y * 64;
    const int n0 = blockIdx.x * 64;

    const int arow = t >> 2, ac0 = (t & 3) << 3;   // 64 rows x 32 k
    const int brow = t >> 3, bc0 = (t & 7) << 3;   // 32 k    x 64 n

    f32x4 acc[4];
    #pragma unroll
    for (int i = 0; i < 4; i++)
        for (int r = 0; r < 4; r++) acc[i][r] = 0.f;

    for (int kk = 0; kk < K; kk += 32) {
        // ---- stage A tile -> LDS bf16 [m][k]
        if constexpr (A_BF16) {
            const unsigned short* Ap = (const unsigned short*)Ain + (size_t)(m0 + arow)*K + kk + ac0;
            *(uint4*)&Asl[arow][ac0] = *(const uint4*)Ap;
        } else {
            const float* Ap = (const float*)Ain + (size_t)(m0 + arow)*K + kk + ac0;
            float4 a0 = *(const float4*)Ap;
            float4 a1 = *(const float4*)(Ap + 4);
            uint4 p;
            p.x = (unsigned)f2b(a0.x) | ((unsigned)f2b(a0.y) << 16);
            p.y = (unsigned)f2b(a0.z) | ((unsigned)f2b(a0.w) << 16);
            p.z = (unsigned)f2b(a1.x) | ((unsigned)f2b(a1.y) << 16);
            p.w = (unsigned)f2b(a1.z) | ((unsigned)f2b(a1.w) << 16);
            *(uint4*)&Asl[arow][ac0] = p;
        }
        // ---- stage B tile transposed -> LDS bf16 [n][k]
        {
            const float* Wp = W + (size_t)(kk + brow)*N + n0 + bc0;
            float4 b0 = *(const float4*)Wp;
            float4 b1 = *(const float4*)(Wp + 4);
            Bsl[bc0+0][brow] = f2b(b0.x);
            Bsl[bc0+1][brow] = f2b(b0.y);
            Bsl[bc0+2][brow] = f2b(b0.z);
            Bsl[bc0+3][brow] = f2b(b0.w);
            Bsl[bc0+4][brow] = f2b(b1.x);
            Bsl[bc0+5][brow] = f2b(b1.y);
            Bsl[bc0+6][brow] = f2b(b1.z);
            Bsl[bc0+7][brow] = f2b(b1.w);
        }
        __syncthreads();

        // A-frag: A[m = wave*16 + l16][k = quad*8 + j]
        short8 af = *(const short8*)&Asl[wave*16 + l16][quad*8];
        #pragma unroll
        for (int nt = 0; nt < 4; nt++) {
            // B-frag: B[k = quad*8 + j][n = nt*16 + l16] == Bsl[n][k]
            short8 bfr = *(const short8*)&Bsl[nt*16 + l16][quad*8];
            acc[nt] = __builtin_amdgcn_mfma_f32_16x16x32_bf16(af, bfr, acc[nt], 0, 0, 0);
        }
        __syncthreads();
    }

    // epilogue: D row = quad*4 + r, col = l16  (verified m89 mapping)
    #pragma unroll
    for (int nt = 0; nt < 4; nt++) {
        int col = n0 + nt*16 + l16;
        float bv = bias[col];
        #pragma unroll
        for (int r = 0; r < 4; r++) {
            int row = m0 + wave*16 + quad*4 + r;
            float v = acc[nt][r] + bv;
            if constexpr (OUT_BF16)
                ((unsigned short*)Cout)[(size_t)row*N + col] = f2b(v);
            else
                ((float*)Cout)[(size_t)row*N + col] = v;
        }
    }
}

__global__ __launch_bounds__(256)
void zero_kernel(float* __restrict__ p, int n)
{
    int i = blockIdx.x * 256 + threadIdx.x;
    if (i < n) p[i] = 0.f;
}

// KtV[b,h][d1][d2] = scale * sum_l K[b,l,h,d1] * V[b,l,h,d2]
// grid: (B*NH, 8 L-chunks of 256); fp32 atomic accumulate.
__global__ __launch_bounds__(256)
void ktv_kernel(const unsigned short* __restrict__ Kb, const unsigned short* __restrict__ Vb,
                float* __restrict__ KtV)
{
    const int bh = blockIdx.x;      // 0..31
    const int chunk = blockIdx.y;   // 0..7
    const int b = bh >> 4, h = bh & 15;
    const int t = threadIdx.x;
    const int d1 = t >> 2;          // 0..63
    const int d2b = (t & 3) << 4;   // 0,16,32,48

    float acc[16];
    #pragma unroll
    for (int j = 0; j < 16; j++) acc[j] = 0.f;

    size_t rowbase = ((size_t)(b*L_ + chunk*256))*DM + h*DH;
    for (int l = 0; l < 256; l++) {
        size_t base = rowbase + (size_t)l*DM;
        float kv = b2f(Kb[base + d1]);
        const unsigned short* vp = Vb + base + d2b;
        uint4 p0 = *(const uint4*)vp;
        uint4 p1 = *(const uint4*)(vp + 8);
        float vv[16];
        vv[0]  = b2f((unsigned short)(p0.x & 0xffff)); vv[1]  = b2f((unsigned short)(p0.x >> 16));
        vv[2]  = b2f((unsigned short)(p0.y & 0xffff)); vv[3]  = b2f((unsigned short)(p0.y >> 16));
        vv[4]  = b2f((unsigned short)(p0.z & 0xffff)); vv[5]  = b2f((unsigned short)(p0.z >> 16));
        vv[6]  = b2f((unsigned short)(p0.w & 0xffff)); vv[7]  = b2f((unsigned short)(p0.w >> 16));
        vv[8]  = b2f((unsigned short)(p1.x & 0xffff)); vv[9]  = b2f((unsigned short)(p1.x >> 16));
        vv[10] = b2f((unsigned short)(p1.y & 0xffff)); vv[11] = b2f((unsigned short)(p1.y >> 16));
        vv[12] = b2f((unsigned short)(p1.z & 0xffff)); vv[13] = b2f((unsigned short)(p1.z >> 16));
        vv[14] = b2f((unsigned short)(p1.w & 0xffff)); vv[15] = b2f((unsigned short)(p1.w >> 16));
        #pragma unroll
        for (int j = 0; j < 16; j++) acc[j] += kv * vv[j];
    }
    float* dst = KtV + ((size_t)bh*64 + d1)*64 + d2b;
    #pragma unroll
    for (int j = 0; j < 16; j++) atomicAdd(dst + j, acc[j] * 0.125f);   // scale=1/sqrt(64)
}

// attn[m][h*64+d] = sum_d1 Q[m][h*64+d1] * KtV[b,h][d1][d]  (bf16 out)
__global__ __launch_bounds__(256)
void qktv_kernel(const unsigned short* __restrict__ Qb, const float* __restrict__ KtV,
                 unsigned short* __restrict__ attn)
{
    __shared__ float qrow[1024];
    const int m = blockIdx.x;        // 0..4095
    const int b = m >> 11;
    const int t = threadIdx.x;

    uint2 q4 = *(const uint2*)(Qb + (size_t)m*DM + t*4);
    qrow[t*4+0] = b2f((unsigned short)(q4.x & 0xffff));
    qrow[t*4+1] = b2f((unsigned short)(q4.x >> 16));
    qrow[t*4+2] = b2f((unsigned short)(q4.y & 0xffff));
    qrow[t*4+3] = b2f((unsigned short)(q4.y >> 16));
    __syncthreads();

    const int c0 = t*4;
    const int h  = c0 >> 6;
    const int dc = c0 & 63;
    const float* kt = KtV + ((size_t)(b*NH + h) * 64) * 64 + dc;
    const float* qh = qrow + (h << 6);

    float a0=0.f, a1=0.f, a2=0.f, a3=0.f;
    #pragma unroll 8
    for (int d1 = 0; d1 < 64; d1++) {
        float qv = qh[d1];
        float4 kv = *(const float4*)(kt + (size_t)d1*64);
        a0 += qv*kv.x; a1 += qv*kv.y; a2 += qv*kv.z; a3 += qv*kv.w;
    }
    uint2 o;
    o.x = (unsigned)f2b(a0) | ((unsigned)f2b(a1) << 16);
    o.y = (unsigned)f2b(a2) | ((unsigned)f2b(a3) << 16);
    *(uint2*)(attn + (size_t)m*DM + c0) = o;
}

extern "C" void kernel_launch(void* const* d_in, const int* in_sizes, int n_in,
                              void* d_out, int out_size, void* d_ws, size_t ws_size,
                              hipStream_t stream)
{
    const float* x  = (const float*)d_in[0];
    const float* Wq = (const float*)d_in[1];
    const float* bq = (const float*)d_in[2];
    const float* Wk = (const float*)d_in[3];
    const float* bk = (const float*)d_in[4];
    const float* Wv = (const float*)d_in[5];
    const float* bv = (const float*)d_in[6];
    const float* Wo = (const float*)d_in[7];
    const float* bo = (const float*)d_in[8];

    char* ws = (char*)d_ws;
    unsigned short* Qb  = (unsigned short*)(ws);                           // 8 MB
    unsigned short* Kb  = (unsigned short*)(ws + (size_t)8*1024*1024);     // 8 MB
    unsigned short* Vb  = (unsigned short*)(ws + (size_t)16*1024*1024);    // 8 MB
    float*          KtV = (float*)(ws + (size_t)24*1024*1024);             // 512 KB
    unsigned short* attn = Kb;  // alias: Kb dead after ktv_kernel

    dim3 gg(DM/64, M_/64);  // (16, 64)
    gemm_bias_kernel<false, true><<<gg, 256, 0, stream>>>(x, Wq, bq, Qb, M_, DM, DM);
    gemm_bias_kernel<false, true><<<gg, 256, 0, stream>>>(x, Wk, bk, Kb, M_, DM, DM);
    gemm_bias_kernel<false, true><<<gg, 256, 0, stream>>>(x, Wv, bv, Vb, M_, DM, DM);

    zero_kernel<<<(B_*NH*DH*DH + 255)/256, 256, 0, stream>>>(KtV, B_*NH*DH*DH);
    ktv_kernel<<<dim3(B_*NH, 8), 256, 0, stream>>>(Kb, Vb, KtV);
    qktv_kernel<<<M_, 256, 0, stream>>>(Qb, KtV, attn);

    gemm_bias_kernel<true, false><<<gg, 256, 0, stream>>>(attn, Wo, bo, d_out, M_, DM, DM);
}

// Round 2
// 309.683 us; speedup vs baseline: 1.4246x; 1.4246x over previous
//
#include <hip/hip_runtime.h>
#include <stdint.h>

#define B_ 2
#define L_ 2048
#define DM 1024
#define NH 16
#define DH 64
#define M_ (B_*L_)   // 4096

typedef short short8 __attribute__((ext_vector_type(8)));
typedef float f32x4 __attribute__((ext_vector_type(4)));

__device__ __forceinline__ unsigned short f2b(float f) {
    union { float f; unsigned int u; } v; v.f = f;
    unsigned int u = v.u;
    unsigned int r = (u + 0x7fffu + ((u >> 16) & 1u)) >> 16;   // RNE
    return (unsigned short)r;
}
__device__ __forceinline__ float b2f(unsigned short h) {
    union { unsigned int u; float f; } v; v.u = ((unsigned int)h) << 16;
    return v.f;
}

// C[M][N] = A[M][K] * W[K][N] + bias.  A: fp32 or bf16 (row-major). W: fp32 row-major.
// Out: bf16 or fp32. 64x64 tile, BK=32, 256 threads (4 waves), MFMA 16x16x32 bf16.
template<bool A_BF16, bool OUT_BF16>
__global__ __launch_bounds__(256)
void gemm_bias_kernel(const void* __restrict__ Ain, const float* __restrict__ W,
                      const float* __restrict__ bias, void* __restrict__ Cout,
                      int M, int N, int K)
{
    // stride 40 elems (=80B, 16B-aligned rows): worst 2-way bank aliasing (free)
    __shared__ __align__(16) unsigned short Asl[64][40];  // A[m][k]
    __shared__ __align__(16) unsigned short Bsl[64][40];  // B^T: [n][k]

    const int t    = threadIdx.x;
    const int wave = t >> 6, lane = t & 63;
    const int quad = lane >> 4, l16 = lane & 15;
    const int m0 = blockIdx.y * 64;
    const int n0 = blockIdx.x * 64;

    const int arow = t >> 2, ac0 = (t & 3) << 3;   // 64 rows x 32 k
    const int brow = t >> 3, bc0 = (t & 7) << 3;   // 32 k    x 64 n

    f32x4 acc[4];
    #pragma unroll
    for (int i = 0; i < 4; i++)
        for (int r = 0; r < 4; r++) acc[i][r] = 0.f;

    for (int kk = 0; kk < K; kk += 32) {
        // ---- stage A tile -> LDS bf16 [m][k]
        if constexpr (A_BF16) {
            const unsigned short* Ap = (const unsigned short*)Ain + (size_t)(m0 + arow)*K + kk + ac0;
            *(uint4*)&Asl[arow][ac0] = *(const uint4*)Ap;
        } else {
            const float* Ap = (const float*)Ain + (size_t)(m0 + arow)*K + kk + ac0;
            float4 a0 = *(const float4*)Ap;
            float4 a1 = *(const float4*)(Ap + 4);
            uint4 p;
            p.x = (unsigned)f2b(a0.x) | ((unsigned)f2b(a0.y) << 16);
            p.y = (unsigned)f2b(a0.z) | ((unsigned)f2b(a0.w) << 16);
            p.z = (unsigned)f2b(a1.x) | ((unsigned)f2b(a1.y) << 16);
            p.w = (unsigned)f2b(a1.z) | ((unsigned)f2b(a1.w) << 16);
            *(uint4*)&Asl[arow][ac0] = p;
        }
        // ---- stage B tile transposed -> LDS bf16 [n][k]
        {
            const float* Wp = W + (size_t)(kk + brow)*N + n0 + bc0;
            float4 b0 = *(const float4*)Wp;
            float4 b1 = *(const float4*)(Wp + 4);
            Bsl[bc0+0][brow] = f2b(b0.x);
            Bsl[bc0+1][brow] = f2b(b0.y);
            Bsl[bc0+2][brow] = f2b(b0.z);
            Bsl[bc0+3][brow] = f2b(b0.w);
            Bsl[bc0+4][brow] = f2b(b1.x);
            Bsl[bc0+5][brow] = f2b(b1.y);
            Bsl[bc0+6][brow] = f2b(b1.z);
            Bsl[bc0+7][brow] = f2b(b1.w);
        }
        __syncthreads();

        // A-frag: A[m = wave*16 + l16][k = quad*8 + j]
        short8 af = *(const short8*)&Asl[wave*16 + l16][quad*8];
        #pragma unroll
        for (int nt = 0; nt < 4; nt++) {
            // B-frag: B[k][n = nt*16 + l16] == Bsl[n][k]
            short8 bfr = *(const short8*)&Bsl[nt*16 + l16][quad*8];
            acc[nt] = __builtin_amdgcn_mfma_f32_16x16x32_bf16(af, bfr, acc[nt], 0, 0, 0);
        }
        __syncthreads();
    }

    // epilogue: D row = quad*4 + r, col = l16  (verified m89 mapping)
    #pragma unroll
    for (int nt = 0; nt < 4; nt++) {
        int col = n0 + nt*16 + l16;
        float bv = bias[col];
        #pragma unroll
        for (int r = 0; r < 4; r++) {
            int row = m0 + wave*16 + quad*4 + r;
            float v = acc[nt][r] + bv;
            if constexpr (OUT_BF16)
                ((unsigned short*)Cout)[(size_t)row*N + col] = f2b(v);
            else
                ((float*)Cout)[(size_t)row*N + col] = v;
        }
    }
}

__global__ __launch_bounds__(256)
void zero_kernel(float* __restrict__ p, int n)
{
    int i = blockIdx.x * 256 + threadIdx.x;
    if (i < n) p[i] = 0.f;
}

// KtV[bh][d1][d2] += 0.125 * sum_{l in chunk} K[b,l,h,d1] * V[b,l,h,d2]
// MFMA formulation: C[m=d1][n=d2] = sum_k=l A[d1][l]*B[l][d2].
// grid (B*NH, 8); 256 threads; split-K over 8 L-chunks via fp32 atomics.
__global__ __launch_bounds__(256)
void ktv_mfma_kernel(const unsigned short* __restrict__ Kb, const unsigned short* __restrict__ Vb,
                     float* __restrict__ KtV)
{
    __shared__ __align__(16) unsigned short Ksl[64][40];  // [d1][l]
    __shared__ __align__(16) unsigned short Vsl[64][40];  // [d2][l]

    const int bh = blockIdx.x, chunk = blockIdx.y;
    const int b = bh >> 4, h = bh & 15;
    const int t = threadIdx.x;
    const int wave = t >> 6, lane = t & 63;
    const int quad = lane >> 4, l16 = lane & 15;
    const int lrow = t >> 3, c0 = (t & 7) << 3;   // 32 l-rows x 8 d-cols of 8

    f32x4 acc[4];
    #pragma unroll
    for (int i = 0; i < 4; i++)
        for (int r = 0; r < 4; r++) acc[i][r] = 0.f;

    const size_t base0 = ((size_t)(b*L_ + chunk*256))*DM + (size_t)h*DH;
    for (int kk = 0; kk < 256; kk += 32) {
        size_t rb = base0 + (size_t)(kk + lrow)*DM + c0;
        uint4 kp = *(const uint4*)(Kb + rb);
        uint4 vp = *(const uint4*)(Vb + rb);
        // transpose-scatter 8 bf16 into [d][l]
        Ksl[c0+0][lrow] = (unsigned short)(kp.x & 0xffff);
        Ksl[c0+1][lrow] = (unsigned short)(kp.x >> 16);
        Ksl[c0+2][lrow] = (unsigned short)(kp.y & 0xffff);
        Ksl[c0+3][lrow] = (unsigned short)(kp.y >> 16);
        Ksl[c0+4][lrow] = (unsigned short)(kp.z & 0xffff);
        Ksl[c0+5][lrow] = (unsigned short)(kp.z >> 16);
        Ksl[c0+6][lrow] = (unsigned short)(kp.w & 0xffff);
        Ksl[c0+7][lrow] = (unsigned short)(kp.w >> 16);
        Vsl[c0+0][lrow] = (unsigned short)(vp.x & 0xffff);
        Vsl[c0+1][lrow] = (unsigned short)(vp.x >> 16);
        Vsl[c0+2][lrow] = (unsigned short)(vp.y & 0xffff);
        Vsl[c0+3][lrow] = (unsigned short)(vp.y >> 16);
        Vsl[c0+4][lrow] = (unsigned short)(vp.z & 0xffff);
        Vsl[c0+5][lrow] = (unsigned short)(vp.z >> 16);
        Vsl[c0+6][lrow] = (unsigned short)(vp.w & 0xffff);
        Vsl[c0+7][lrow] = (unsigned short)(vp.w >> 16);
        __syncthreads();

        short8 af = *(const short8*)&Ksl[wave*16 + l16][quad*8];
        #pragma unroll
        for (int nt = 0; nt < 4; nt++) {
            short8 bfr = *(const short8*)&Vsl[nt*16 + l16][quad*8];
            acc[nt] = __builtin_amdgcn_mfma_f32_16x16x32_bf16(af, bfr, acc[nt], 0, 0, 0);
        }
        __syncthreads();
    }

    float* dst0 = KtV + (size_t)bh*64*64;
    #pragma unroll
    for (int nt = 0; nt < 4; nt++) {
        int col = nt*16 + l16;
        #pragma unroll
        for (int r = 0; r < 4; r++) {
            int row = wave*16 + quad*4 + r;
            atomicAdd(dst0 + row*64 + col, acc[nt][r] * 0.125f);
        }
    }
}

// attn[m][h*64+d2] = sum_d1 Q[m][h*64+d1] * KtV[bh][d1][d2]   (bf16 out)
// grid (B*NH, 32 m-tiles of 64); one 64x64x64 MFMA GEMM per block.
__global__ __launch_bounds__(256)
void qktv_mfma_kernel(const unsigned short* __restrict__ Qb, const float* __restrict__ KtV,
                      unsigned short* __restrict__ attn)
{
    __shared__ __align__(16) unsigned short Qsl[64][72];  // [m][d1]
    __shared__ __align__(16) unsigned short Bsl[64][72];  // [d2][d1]

    const int bh = blockIdx.x, mt = blockIdx.y;
    const int b = bh >> 4, h = bh & 15;
    const int t = threadIdx.x;
    const int wave = t >> 6, lane = t & 63;
    const int quad = lane >> 4, l16 = lane & 15;
    const int m0 = b*L_ + mt*64;          // global row base
    const int row = t >> 2, c0 = (t & 3) << 4;   // 64 rows x 4 col-groups of 16

    // stage Q tile [m][d1], vectorized
    const unsigned short* qp = Qb + (size_t)(m0 + row)*DM + h*DH + c0;
    *(uint4*)&Qsl[row][c0]     = *(const uint4*)qp;
    *(uint4*)&Qsl[row][c0 + 8] = *(const uint4*)(qp + 8);

    // stage KtV transposed + converted -> [d2][d1] bf16
    const float* kp = KtV + ((size_t)bh*64 + row)*64 + c0;
    #pragma unroll
    for (int j = 0; j < 16; j++) Bsl[c0 + j][row] = f2b(kp[j]);
    __syncthreads();

    f32x4 acc[4];
    #pragma unroll
    for (int i = 0; i < 4; i++)
        for (int r = 0; r < 4; r++) acc[i][r] = 0.f;

    #pragma unroll
    for (int ks = 0; ks < 2; ks++) {
        short8 af = *(const short8*)&Qsl[wave*16 + l16][ks*32 + quad*8];
        #pragma unroll
        for (int nt = 0; nt < 4; nt++) {
            short8 bfr = *(const short8*)&Bsl[nt*16 + l16][ks*32 + quad*8];
            acc[nt] = __builtin_amdgcn_mfma_f32_16x16x32_bf16(af, bfr, acc[nt], 0, 0, 0);
        }
    }

    #pragma unroll
    for (int nt = 0; nt < 4; nt++) {
        int col = h*DH + nt*16 + l16;
        #pragma unroll
        for (int r = 0; r < 4; r++) {
            int grow = m0 + wave*16 + quad*4 + r;
            attn[(size_t)grow*DM + col] = f2b(acc[nt][r]);
        }
    }
}

extern "C" void kernel_launch(void* const* d_in, const int* in_sizes, int n_in,
                              void* d_out, int out_size, void* d_ws, size_t ws_size,
                              hipStream_t stream)
{
    const float* x  = (const float*)d_in[0];
    const float* Wq = (const float*)d_in[1];
    const float* bq = (const float*)d_in[2];
    const float* Wk = (const float*)d_in[3];
    const float* bk = (const float*)d_in[4];
    const float* Wv = (const float*)d_in[5];
    const float* bv = (const float*)d_in[6];
    const float* Wo = (const float*)d_in[7];
    const float* bo = (const float*)d_in[8];

    char* ws = (char*)d_ws;
    unsigned short* Qb  = (unsigned short*)(ws);                           // 8 MB
    unsigned short* Kb  = (unsigned short*)(ws + (size_t)8*1024*1024);     // 8 MB
    unsigned short* Vb  = (unsigned short*)(ws + (size_t)16*1024*1024);    // 8 MB
    float*          KtV = (float*)(ws + (size_t)24*1024*1024);             // 512 KB
    unsigned short* attn = Kb;  // alias: Kb dead after ktv

    dim3 gg(DM/64, M_/64);  // (16, 64)
    gemm_bias_kernel<false, true><<<gg, 256, 0, stream>>>(x, Wq, bq, Qb, M_, DM, DM);
    gemm_bias_kernel<false, true><<<gg, 256, 0, stream>>>(x, Wk, bk, Kb, M_, DM, DM);
    gemm_bias_kernel<false, true><<<gg, 256, 0, stream>>>(x, Wv, bv, Vb, M_, DM, DM);

    zero_kernel<<<(B_*NH*DH*DH + 255)/256, 256, 0, stream>>>(KtV, B_*NH*DH*DH);
    ktv_mfma_kernel<<<dim3(B_*NH, 8), 256, 0, stream>>>(Kb, Vb, KtV);
    qktv_mfma_kernel<<<dim3(B_*NH, L_/64), 256, 0, stream>>>(Qb, KtV, attn);

    gemm_bias_kernel<true, false><<<gg, 256, 0, stream>>>(attn, Wo, bo, d_out, M_, DM, DM);
}

// Round 3
// 181.358 us; speedup vs baseline: 2.4325x; 1.7076x over previous
//
#include <hip/hip_runtime.h>
#include <stdint.h>

#define B_ 2
#define L_ 2048
#define DM 1024
#define NH 16
#define DH 64
#define M_ (B_*L_)     // 4096
#define NQKV 3072

typedef short short8 __attribute__((ext_vector_type(8)));
typedef float f32x4 __attribute__((ext_vector_type(4)));

__device__ __forceinline__ unsigned short f2b(float f) {
    union { float f; unsigned int u; } v; v.f = f;
    unsigned int u = v.u;
    return (unsigned short)((u + 0x7fffu + ((u >> 16) & 1u)) >> 16);   // RNE
}

__device__ __forceinline__ void gld_lds16(const void* g, void* l) {
    __builtin_amdgcn_global_load_lds(
        (const __attribute__((address_space(1))) void*)g,
        (__attribute__((address_space(3))) void*)l, 16, 0, 0);
}

// ---------------- conversion kernels (once per call, memory-bound) ------------

__global__ __launch_bounds__(256)
void cvt_bf16_kernel(const float* __restrict__ in, unsigned short* __restrict__ out, int n)
{
    int i = (blockIdx.x * 256 + threadIdx.x) * 8;
    if (i >= n) return;
    float4 a0 = *(const float4*)(in + i);
    float4 a1 = *(const float4*)(in + i + 4);
    uint4 p;
    p.x = (unsigned)f2b(a0.x) | ((unsigned)f2b(a0.y) << 16);
    p.y = (unsigned)f2b(a0.z) | ((unsigned)f2b(a0.w) << 16);
    p.z = (unsigned)f2b(a1.x) | ((unsigned)f2b(a1.y) << 16);
    p.w = (unsigned)f2b(a1.z) | ((unsigned)f2b(a1.w) << 16);
    *(uint4*)(out + i) = p;
}

// W [K][N] fp32 -> Wt [.][K] bf16 rows [n_off, n_off+N); 32x32 tile via LDS
__global__ __launch_bounds__(256)
void cvt_wt_kernel(const float* __restrict__ W, unsigned short* __restrict__ Wt,
                   int K, int N, int n_off)
{
    __shared__ float tile[32][33];
    const int k0 = blockIdx.y * 32, n0 = blockIdx.x * 32;
    const int t = threadIdx.x;
    const int r = t >> 3, c4 = (t & 7) << 2;
    float4 v = *(const float4*)(W + (size_t)(k0 + r) * N + n0 + c4);
    tile[r][c4+0] = v.x; tile[r][c4+1] = v.y; tile[r][c4+2] = v.z; tile[r][c4+3] = v.w;
    __syncthreads();
    // write Wt[n_off+n0+r][k0 + c4 .. +3]
    uint2 o;
    o.x = (unsigned)f2b(tile[c4+0][r]) | ((unsigned)f2b(tile[c4+1][r]) << 16);
    o.y = (unsigned)f2b(tile[c4+2][r]) | ((unsigned)f2b(tile[c4+3][r]) << 16);
    *(uint2*)(Wt + (size_t)(n_off + n0 + r) * K + k0 + c4) = o;
}

__global__ __launch_bounds__(256)
void pack_bias_kernel(const float* __restrict__ bq, const float* __restrict__ bk,
                      const float* __restrict__ bv, float* __restrict__ dst)
{
    int i = blockIdx.x * 256 + threadIdx.x;   // 0..3071
    float v = (i < 1024) ? bq[i] : (i < 2048 ? bk[i - 1024] : bv[i - 2048]);
    dst[i] = v;
}

__global__ __launch_bounds__(256)
void zero_kernel(float* __restrict__ p, int n)
{
    int i = blockIdx.x * 256 + threadIdx.x;
    if (i < n) p[i] = 0.f;
}

// ---------------- m97-style 128x128 GEMM, A[M][K] bf16 x Bt[N][K] bf16 -------
// XOR chunk swizzle: LDS row r slot s (16B each, 4/row) holds k-chunk s^((r>>1)&3)
// -> ds_read_b128 fragment reads are exactly 2-way bank-aliased (free, m136),
//    and layout is packed (global_load_lds wave-uniform base + lane*16).
template<bool OUT_BF16>
__global__ __launch_bounds__(256)
void gemm_tn_kernel(const unsigned short* __restrict__ A,
                    const unsigned short* __restrict__ Bt,
                    const float* __restrict__ bias,
                    void* __restrict__ C,
                    int M, int N, int K)
{
    __shared__ __align__(16) unsigned short As[128 * 32];
    __shared__ __align__(16) unsigned short Bs[128 * 32];

    const int t = threadIdx.x;
    const int w = t >> 6, lane = t & 63;
    const int quad = lane >> 4, l16 = lane & 15;
    const int wm = w >> 1, wn = w & 1;
    const int m0 = blockIdx.y * 128, n0 = blockIdx.x * 128;

    f32x4 acc[4][4];
    #pragma unroll
    for (int i = 0; i < 4; i++)
        #pragma unroll
        for (int j = 0; j < 4; j++)
            #pragma unroll
            for (int r = 0; r < 4; r++) acc[i][j][r] = 0.f;

    const int srow = t >> 2;        // 0..63
    const int schunk = t & 3;

    for (int kk = 0; kk < K; kk += 32) {
        #pragma unroll
        for (int p = 0; p < 2; p++) {
            int row = p * 64 + srow;
            int g = schunk ^ ((row >> 1) & 3);
            const unsigned short* ga = A  + (size_t)(m0 + row) * K + kk + g * 8;
            const unsigned short* gb = Bt + (size_t)(n0 + row) * K + kk + g * 8;
            // wave-uniform LDS dest; HW scatters lane*16
            char* la = (char*)As + p * 4096 + w * 1024;
            char* lb = (char*)Bs + p * 4096 + w * 1024;
            gld_lds16(ga, la);
            gld_lds16(gb, lb);
        }
        __syncthreads();

        short8 afr[4], bfr[4];
        #pragma unroll
        for (int i = 0; i < 4; i++) {
            int am = wm * 64 + i * 16 + l16;
            afr[i] = *(const short8*)((const char*)As + am * 64 + ((quad ^ ((am >> 1) & 3)) << 4));
            int bn = wn * 64 + i * 16 + l16;
            bfr[i] = *(const short8*)((const char*)Bs + bn * 64 + ((quad ^ ((bn >> 1) & 3)) << 4));
        }
        #pragma unroll
        for (int i = 0; i < 4; i++)
            #pragma unroll
            for (int j = 0; j < 4; j++)
                acc[i][j] = __builtin_amdgcn_mfma_f32_16x16x32_bf16(afr[i], bfr[j], acc[i][j], 0, 0, 0);
        __syncthreads();
    }

    #pragma unroll
    for (int j = 0; j < 4; j++) {
        int col = n0 + wn * 64 + j * 16 + l16;
        float bv = bias[col];
        #pragma unroll
        for (int i = 0; i < 4; i++) {
            #pragma unroll
            for (int r = 0; r < 4; r++) {
                int row = m0 + wm * 64 + i * 16 + quad * 4 + r;
                float v = acc[i][j][r] + bv;
                if constexpr (OUT_BF16)
                    ((unsigned short*)C)[(size_t)row * N + col] = f2b(v);
                else
                    ((float*)C)[(size_t)row * N + col] = v;
            }
        }
    }
}

// ---------------- attention (linear, no softmax): KtV then Q@KtV -------------

// KtV[bh][d1][d2] += 0.125 * sum_l K[b,l,h,d1] * V[b,l,h,d2]; QKV layout stride 3072
__global__ __launch_bounds__(256)
void ktv_mfma_kernel(const unsigned short* __restrict__ QKV, float* __restrict__ KtV)
{
    __shared__ __align__(16) unsigned short Ksl[64][40];  // [d1][l]
    __shared__ __align__(16) unsigned short Vsl[64][40];  // [d2][l]

    const int bh = blockIdx.x, chunk = blockIdx.y;
    const int b = bh >> 4, h = bh & 15;
    const int t = threadIdx.x;
    const int wave = t >> 6, lane = t & 63;
    const int quad = lane >> 4, l16 = lane & 15;
    const int lrow = t >> 3, c0 = (t & 7) << 3;

    f32x4 acc[4];
    #pragma unroll
    for (int i = 0; i < 4; i++)
        #pragma unroll
        for (int r = 0; r < 4; r++) acc[i][r] = 0.f;

    const size_t base0 = ((size_t)(b * L_ + chunk * 256)) * NQKV + (size_t)h * DH;
    for (int kk = 0; kk < 256; kk += 32) {
        size_t rb = base0 + (size_t)(kk + lrow) * NQKV + c0;
        uint4 kp = *(const uint4*)(QKV + rb + 1024);
        uint4 vp = *(const uint4*)(QKV + rb + 2048);
        Ksl[c0+0][lrow] = (unsigned short)(kp.x & 0xffff);
        Ksl[c0+1][lrow] = (unsigned short)(kp.x >> 16);
        Ksl[c0+2][lrow] = (unsigned short)(kp.y & 0xffff);
        Ksl[c0+3][lrow] = (unsigned short)(kp.y >> 16);
        Ksl[c0+4][lrow] = (unsigned short)(kp.z & 0xffff);
        Ksl[c0+5][lrow] = (unsigned short)(kp.z >> 16);
        Ksl[c0+6][lrow] = (unsigned short)(kp.w & 0xffff);
        Ksl[c0+7][lrow] = (unsigned short)(kp.w >> 16);
        Vsl[c0+0][lrow] = (unsigned short)(vp.x & 0xffff);
        Vsl[c0+1][lrow] = (unsigned short)(vp.x >> 16);
        Vsl[c0+2][lrow] = (unsigned short)(vp.y & 0xffff);
        Vsl[c0+3][lrow] = (unsigned short)(vp.y >> 16);
        Vsl[c0+4][lrow] = (unsigned short)(vp.z & 0xffff);
        Vsl[c0+5][lrow] = (unsigned short)(vp.z >> 16);
        Vsl[c0+6][lrow] = (unsigned short)(vp.w & 0xffff);
        Vsl[c0+7][lrow] = (unsigned short)(vp.w >> 16);
        __syncthreads();

        short8 af = *(const short8*)&Ksl[wave * 16 + l16][quad * 8];
        #pragma unroll
        for (int nt = 0; nt < 4; nt++) {
            short8 bfr = *(const short8*)&Vsl[nt * 16 + l16][quad * 8];
            acc[nt] = __builtin_amdgcn_mfma_f32_16x16x32_bf16(af, bfr, acc[nt], 0, 0, 0);
        }
        __syncthreads();
    }

    float* dst0 = KtV + (size_t)bh * 64 * 64;
    #pragma unroll
    for (int nt = 0; nt < 4; nt++) {
        int col = nt * 16 + l16;
        #pragma unroll
        for (int r = 0; r < 4; r++) {
            int row = wave * 16 + quad * 4 + r;
            atomicAdd(dst0 + row * 64 + col, acc[nt][r] * 0.125f);
        }
    }
}

// attn[m][h*64+d2] = sum_d1 Q[m][h*64+d1] * KtV[bh][d1][d2]; Q from QKV (stride 3072)
__global__ __launch_bounds__(256)
void qktv_mfma_kernel(const unsigned short* __restrict__ QKV, const float* __restrict__ KtV,
                      unsigned short* __restrict__ attn)
{
    __shared__ __align__(16) unsigned short Qsl[64][72];  // [m][d1]
    __shared__ __align__(16) unsigned short Bsl[64][72];  // [d2][d1]

    const int bh = blockIdx.x, mt = blockIdx.y;
    const int b = bh >> 4, h = bh & 15;
    const int t = threadIdx.x;
    const int wave = t >> 6, lane = t & 63;
    const int quad = lane >> 4, l16 = lane & 15;
    const int m0 = b * L_ + mt * 64;
    const int row = t >> 2, c0 = (t & 3) << 4;

    const unsigned short* qp = QKV + (size_t)(m0 + row) * NQKV + h * DH + c0;
    *(uint4*)&Qsl[row][c0]     = *(const uint4*)qp;
    *(uint4*)&Qsl[row][c0 + 8] = *(const uint4*)(qp + 8);

    const float* kp = KtV + ((size_t)bh * 64 + row) * 64 + c0;
    #pragma unroll
    for (int j = 0; j < 16; j++) Bsl[c0 + j][row] = f2b(kp[j]);
    __syncthreads();

    f32x4 acc[4];
    #pragma unroll
    for (int i = 0; i < 4; i++)
        #pragma unroll
        for (int r = 0; r < 4; r++) acc[i][r] = 0.f;

    #pragma unroll
    for (int ks = 0; ks < 2; ks++) {
        short8 af = *(const short8*)&Qsl[wave * 16 + l16][ks * 32 + quad * 8];
        #pragma unroll
        for (int nt = 0; nt < 4; nt++) {
            short8 bfr = *(const short8*)&Bsl[nt * 16 + l16][ks * 32 + quad * 8];
            acc[nt] = __builtin_amdgcn_mfma_f32_16x16x32_bf16(af, bfr, acc[nt], 0, 0, 0);
        }
    }

    #pragma unroll
    for (int nt = 0; nt < 4; nt++) {
        int col = h * DH + nt * 16 + l16;
        #pragma unroll
        for (int r = 0; r < 4; r++) {
            int grow = m0 + wave * 16 + quad * 4 + r;
            attn[(size_t)grow * DM + col] = f2b(acc[nt][r]);
        }
    }
}

// ---------------- launch ------------------------------------------------------

extern "C" void kernel_launch(void* const* d_in, const int* in_sizes, int n_in,
                              void* d_out, int out_size, void* d_ws, size_t ws_size,
                              hipStream_t stream)
{
    const float* x  = (const float*)d_in[0];
    const float* Wq = (const float*)d_in[1];
    const float* bq = (const float*)d_in[2];
    const float* Wk = (const float*)d_in[3];
    const float* bk = (const float*)d_in[4];
    const float* Wv = (const float*)d_in[5];
    const float* bv = (const float*)d_in[6];
    const float* Wo = (const float*)d_in[7];
    const float* bo = (const float*)d_in[8];

    char* ws = (char*)d_ws;
    unsigned short* xb    = (unsigned short*)(ws);                              // 8 MB
    unsigned short* WqkvT = (unsigned short*)(ws + (size_t)8  * 1024 * 1024);   // 6 MB
    unsigned short* WoT   = (unsigned short*)(ws + (size_t)14 * 1024 * 1024);   // 2 MB
    float*          biasq = (float*)         (ws + (size_t)16 * 1024 * 1024);   // 12 KB
    unsigned short* QKV   = (unsigned short*)(ws + (size_t)17 * 1024 * 1024);   // 24 MB
    float*          KtV   = (float*)         (ws + (size_t)41 * 1024 * 1024);   // 512 KB
    unsigned short* attn  = xb;  // xb dead after QKV GEMM

    // phase 0: conversions
    cvt_bf16_kernel<<<(M_ * DM / 8 + 255) / 256, 256, 0, stream>>>(x, xb, M_ * DM);
    dim3 wtg(DM / 32, DM / 32);   // (32,32)
    cvt_wt_kernel<<<wtg, 256, 0, stream>>>(Wq, WqkvT, DM, DM, 0);
    cvt_wt_kernel<<<wtg, 256, 0, stream>>>(Wk, WqkvT, DM, DM, 1024);
    cvt_wt_kernel<<<wtg, 256, 0, stream>>>(Wv, WqkvT, DM, DM, 2048);
    cvt_wt_kernel<<<wtg, 256, 0, stream>>>(Wo, WoT,   DM, DM, 0);
    pack_bias_kernel<<<NQKV / 256, 256, 0, stream>>>(bq, bk, bv, biasq);
    zero_kernel<<<(B_ * NH * DH * DH + 255) / 256, 256, 0, stream>>>(KtV, B_ * NH * DH * DH);

    // phase 1: fused QKV projection  [4096 x 3072 x 1024]
    gemm_tn_kernel<true><<<dim3(NQKV / 128, M_ / 128), 256, 0, stream>>>(
        xb, WqkvT, biasq, QKV, M_, NQKV, DM);

    // phase 2: linear attention via K^T V
    ktv_mfma_kernel<<<dim3(B_ * NH, 8), 256, 0, stream>>>(QKV, KtV);
    qktv_mfma_kernel<<<dim3(B_ * NH, L_ / 64), 256, 0, stream>>>(QKV, KtV, attn);

    // phase 3: output projection  [4096 x 1024 x 1024]
    gemm_tn_kernel<false><<<dim3(DM / 128, M_ / 128), 256, 0, stream>>>(
        attn, WoT, bo, d_out, M_, DM, DM);
}

// Round 4
// 167.586 us; speedup vs baseline: 2.6324x; 1.0822x over previous
//
#include <hip/hip_runtime.h>
#include <stdint.h>

#define B_ 2
#define L_ 2048
#define DM 1024
#define NH 16
#define DH 64
#define M_ (B_*L_)     // 4096
#define NQKV 3072

typedef short short8 __attribute__((ext_vector_type(8)));
typedef float f32x4 __attribute__((ext_vector_type(4)));

__device__ __forceinline__ unsigned short f2b(float f) {
    union { float f; unsigned int u; } v; v.f = f;
    unsigned int u = v.u;
    return (unsigned short)((u + 0x7fffu + ((u >> 16) & 1u)) >> 16);   // RNE
}

__device__ __forceinline__ void gld_lds16(const void* g, void* l) {
    __builtin_amdgcn_global_load_lds(
        (const __attribute__((address_space(1))) void*)g,
        (__attribute__((address_space(3))) void*)l, 16, 0, 0);
}

// ---------------- fused setup: x->bf16, 4x W transpose+cvt, bias pack, zero --
// grid = 2048 (x) + 4096 (W) + 12 (bias) + 128 (zero) = 6284 blocks; whole
// blocks take one branch -> no divergence cost.
__global__ __launch_bounds__(256)
void setup_kernel(const float* __restrict__ x,
                  const float* __restrict__ Wq, const float* __restrict__ Wk,
                  const float* __restrict__ Wv, const float* __restrict__ Wo,
                  const float* __restrict__ bq, const float* __restrict__ bk,
                  const float* __restrict__ bv,
                  unsigned short* __restrict__ xb, unsigned short* __restrict__ WqkvT,
                  unsigned short* __restrict__ WoT, float* __restrict__ biasq,
                  float* __restrict__ KtV)
{
    __shared__ float tile[32][33];
    const int bid = blockIdx.x;
    const int t = threadIdx.x;

    if (bid < 2048) {
        // x [4096][1024] fp32 -> bf16, 8 elems/thread
        int i = (bid * 256 + t) * 8;
        float4 a0 = *(const float4*)(x + i);
        float4 a1 = *(const float4*)(x + i + 4);
        uint4 p;
        p.x = (unsigned)f2b(a0.x) | ((unsigned)f2b(a0.y) << 16);
        p.y = (unsigned)f2b(a0.z) | ((unsigned)f2b(a0.w) << 16);
        p.z = (unsigned)f2b(a1.x) | ((unsigned)f2b(a1.y) << 16);
        p.w = (unsigned)f2b(a1.z) | ((unsigned)f2b(a1.w) << 16);
        *(uint4*)(xb + i) = p;
    } else if (bid < 2048 + 4096) {
        // W [K][N] fp32 -> Wt [n][k] bf16 (32x32 tile via LDS)
        int wb = bid - 2048;
        int wi = wb >> 10;                // 0=Wq 1=Wk 2=Wv 3=Wo
        int tid = wb & 1023;
        const float* W = (wi == 0) ? Wq : (wi == 1) ? Wk : (wi == 2) ? Wv : Wo;
        unsigned short* dst = (wi < 3) ? (WqkvT + (size_t)wi * 1024 * 1024) : WoT;
        int n0 = (tid & 31) * 32, k0 = (tid >> 5) * 32;
        int r = t >> 3, c4 = (t & 7) << 2;
        float4 v = *(const float4*)(W + (size_t)(k0 + r) * DM + n0 + c4);
        tile[r][c4+0] = v.x; tile[r][c4+1] = v.y; tile[r][c4+2] = v.z; tile[r][c4+3] = v.w;
        __syncthreads();
        uint2 o;
        o.x = (unsigned)f2b(tile[c4+0][r]) | ((unsigned)f2b(tile[c4+1][r]) << 16);
        o.y = (unsigned)f2b(tile[c4+2][r]) | ((unsigned)f2b(tile[c4+3][r]) << 16);
        *(uint2*)(dst + (size_t)(n0 + r) * DM + k0 + c4) = o;
    } else if (bid < 2048 + 4096 + 12) {
        int i = (bid - 6144) * 256 + t;   // 0..3071
        float v = (i < 1024) ? bq[i] : (i < 2048 ? bk[i - 1024] : bv[i - 2048]);
        biasq[i] = v;
    } else {
        int i = ((bid - 6156) * 256 + t) * 4;  // zero KtV: 131072 floats
        float4 z; z.x = z.y = z.z = z.w = 0.f;
        *(float4*)(KtV + i) = z;
    }
}

// ---------------- 128xBN GEMM, BK=64, A[M][K] bf16 x Bt[N][K] bf16 ----------
// Packed LDS [row][8 slots of 16B], slot s holds k-chunk s ^ ((row>>1)&7):
// per quarter-wave (16 lanes) frag reads hit 8 slots x 2 lanes = 2-way (free),
// and staging satisfies global_load_lds' wave-uniform-base + lane*16 layout.
template<int BN, bool OUT_BF16>
__global__ __launch_bounds__(256)
void gemm_tn_kernel(const unsigned short* __restrict__ A,
                    const unsigned short* __restrict__ Bt,
                    const float* __restrict__ bias,
                    void* __restrict__ C,
                    int M, int N, int K)
{
    constexpr int BM = 128, BK = 64;
    constexpr int MI = (BN == 128) ? 4 : 2;   // 16-row m-subtiles per wave
    constexpr int MJ = 4;                     // 16-col n-subtiles per wave
    __shared__ __align__(16) unsigned short As[BM * BK];   // 16 KB
    __shared__ __align__(16) unsigned short Bs[BN * BK];   // 16 or 8 KB

    const int t = threadIdx.x;
    const int w = t >> 6, lane = t & 63;
    const int quad = lane >> 4, l16 = lane & 15;
    const int wm = (BN == 128) ? (w >> 1) : w;
    const int wn = (BN == 128) ? (w & 1) : 0;
    const int m0 = blockIdx.y * BM, n0 = blockIdx.x * BN;

    f32x4 acc[MI][MJ];
    #pragma unroll
    for (int i = 0; i < MI; i++)
        #pragma unroll
        for (int j = 0; j < MJ; j++)
            #pragma unroll
            for (int r = 0; r < 4; r++) acc[i][j][r] = 0.f;

    for (int kk = 0; kk < K; kk += BK) {
        #pragma unroll
        for (int p = 0; p < 4; p++) {               // A: 128 rows x 8 chunks
            int c = p * 256 + t;
            int row = c >> 3, slot = c & 7;
            int g = slot ^ ((row >> 1) & 7);
            gld_lds16(A + (size_t)(m0 + row) * K + kk + g * 8,
                      (char*)As + p * 4096 + w * 1024);
        }
        #pragma unroll
        for (int p = 0; p < BN / 32; p++) {         // B: BN rows x 8 chunks
            int c = p * 256 + t;
            int row = c >> 3, slot = c & 7;
            int g = slot ^ ((row >> 1) & 7);
            gld_lds16(Bt + (size_t)(n0 + row) * K + kk + g * 8,
                      (char*)Bs + p * 4096 + w * 1024);
        }
        __syncthreads();

        #pragma unroll
        for (int ks = 0; ks < 2; ks++) {
            int kc = ks * 4 + quad;
            short8 afr[MI], bfr[MJ];
            #pragma unroll
            for (int i = 0; i < MI; i++) {
                int am = wm * (MI * 16) + i * 16 + l16;
                afr[i] = *(const short8*)((const char*)As + am * 128 + ((kc ^ ((am >> 1) & 7)) << 4));
            }
            #pragma unroll
            for (int j = 0; j < MJ; j++) {
                int bn = wn * 64 + j * 16 + l16;
                bfr[j] = *(const short8*)((const char*)Bs + bn * 128 + ((kc ^ ((bn >> 1) & 7)) << 4));
            }
            #pragma unroll
            for (int i = 0; i < MI; i++)
                #pragma unroll
                for (int j = 0; j < MJ; j++)
                    acc[i][j] = __builtin_amdgcn_mfma_f32_16x16x32_bf16(afr[i], bfr[j], acc[i][j], 0, 0, 0);
        }
        __syncthreads();
    }

    #pragma unroll
    for (int j = 0; j < MJ; j++) {
        int col = n0 + wn * 64 + j * 16 + l16;
        float bv = bias[col];
        #pragma unroll
        for (int i = 0; i < MI; i++) {
            #pragma unroll
            for (int r = 0; r < 4; r++) {
                int row = m0 + wm * (MI * 16) + i * 16 + quad * 4 + r;
                float v = acc[i][j][r] + bv;
                if constexpr (OUT_BF16)
                    ((unsigned short*)C)[(size_t)row * N + col] = f2b(v);
                else
                    ((float*)C)[(size_t)row * N + col] = v;
            }
        }
    }
}

// ---------------- linear attention: KtV then Q@KtV ---------------------------

// KtV[bh][d1][d2] += 0.125 * sum_{l in 128-chunk} K[.][d1] * V[.][d2]
// grid (32, 16); split-K via fp32 atomics.
__global__ __launch_bounds__(256)
void ktv_mfma_kernel(const unsigned short* __restrict__ QKV, float* __restrict__ KtV)
{
    __shared__ __align__(16) unsigned short Ksl[64][40];  // [d1][l]
    __shared__ __align__(16) unsigned short Vsl[64][40];  // [d2][l]

    const int bh = blockIdx.x, chunk = blockIdx.y;
    const int b = bh >> 4, h = bh & 15;
    const int t = threadIdx.x;
    const int wave = t >> 6, lane = t & 63;
    const int quad = lane >> 4, l16 = lane & 15;
    const int lrow = t >> 3, c0 = (t & 7) << 3;

    f32x4 acc[4];
    #pragma unroll
    for (int i = 0; i < 4; i++)
        #pragma unroll
        for (int r = 0; r < 4; r++) acc[i][r] = 0.f;

    const size_t base0 = ((size_t)(b * L_ + chunk * 128)) * NQKV + (size_t)h * DH;
    for (int kk = 0; kk < 128; kk += 32) {
        size_t rb = base0 + (size_t)(kk + lrow) * NQKV + c0;
        uint4 kp = *(const uint4*)(QKV + rb + 1024);
        uint4 vp = *(const uint4*)(QKV + rb + 2048);
        Ksl[c0+0][lrow] = (unsigned short)(kp.x & 0xffff);
        Ksl[c0+1][lrow] = (unsigned short)(kp.x >> 16);
        Ksl[c0+2][lrow] = (unsigned short)(kp.y & 0xffff);
        Ksl[c0+3][lrow] = (unsigned short)(kp.y >> 16);
        Ksl[c0+4][lrow] = (unsigned short)(kp.z & 0xffff);
        Ksl[c0+5][lrow] = (unsigned short)(kp.z >> 16);
        Ksl[c0+6][lrow] = (unsigned short)(kp.w & 0xffff);
        Ksl[c0+7][lrow] = (unsigned short)(kp.w >> 16);
        Vsl[c0+0][lrow] = (unsigned short)(vp.x & 0xffff);
        Vsl[c0+1][lrow] = (unsigned short)(vp.x >> 16);
        Vsl[c0+2][lrow] = (unsigned short)(vp.y & 0xffff);
        Vsl[c0+3][lrow] = (unsigned short)(vp.y >> 16);
        Vsl[c0+4][lrow] = (unsigned short)(vp.z & 0xffff);
        Vsl[c0+5][lrow] = (unsigned short)(vp.z >> 16);
        Vsl[c0+6][lrow] = (unsigned short)(vp.w & 0xffff);
        Vsl[c0+7][lrow] = (unsigned short)(vp.w >> 16);
        __syncthreads();

        short8 af = *(const short8*)&Ksl[wave * 16 + l16][quad * 8];
        #pragma unroll
        for (int nt = 0; nt < 4; nt++) {
            short8 bfr = *(const short8*)&Vsl[nt * 16 + l16][quad * 8];
            acc[nt] = __builtin_amdgcn_mfma_f32_16x16x32_bf16(af, bfr, acc[nt], 0, 0, 0);
        }
        __syncthreads();
    }

    float* dst0 = KtV + (size_t)bh * 64 * 64;
    #pragma unroll
    for (int nt = 0; nt < 4; nt++) {
        int col = nt * 16 + l16;
        #pragma unroll
        for (int r = 0; r < 4; r++) {
            int row = wave * 16 + quad * 4 + r;
            atomicAdd(dst0 + row * 64 + col, acc[nt][r] * 0.125f);
        }
    }
}

// attn[m][h*64+d2] = sum_d1 Q[m][h*64+d1] * KtV[bh][d1][d2]; Q from QKV
__global__ __launch_bounds__(256)
void qktv_mfma_kernel(const unsigned short* __restrict__ QKV, const float* __restrict__ KtV,
                      unsigned short* __restrict__ attn)
{
    __shared__ __align__(16) unsigned short Qsl[64][72];  // [m][d1]
    __shared__ __align__(16) unsigned short Bsl[64][72];  // [d2][d1]

    const int bh = blockIdx.x, mt = blockIdx.y;
    const int b = bh >> 4, h = bh & 15;
    const int t = threadIdx.x;
    const int wave = t >> 6, lane = t & 63;
    const int quad = lane >> 4, l16 = lane & 15;
    const int m0 = b * L_ + mt * 64;
    const int row = t >> 2, c0 = (t & 3) << 4;

    const unsigned short* qp = QKV + (size_t)(m0 + row) * NQKV + h * DH + c0;
    *(uint4*)&Qsl[row][c0]     = *(const uint4*)qp;
    *(uint4*)&Qsl[row][c0 + 8] = *(const uint4*)(qp + 8);

    const float* kp = KtV + ((size_t)bh * 64 + row) * 64 + c0;
    #pragma unroll
    for (int j = 0; j < 16; j++) Bsl[c0 + j][row] = f2b(kp[j]);
    __syncthreads();

    f32x4 acc[4];
    #pragma unroll
    for (int i = 0; i < 4; i++)
        #pragma unroll
        for (int r = 0; r < 4; r++) acc[i][r] = 0.f;

    #pragma unroll
    for (int ks = 0; ks < 2; ks++) {
        short8 af = *(const short8*)&Qsl[wave * 16 + l16][ks * 32 + quad * 8];
        #pragma unroll
        for (int nt = 0; nt < 4; nt++) {
            short8 bfr = *(const short8*)&Bsl[nt * 16 + l16][ks * 32 + quad * 8];
            acc[nt] = __builtin_amdgcn_mfma_f32_16x16x32_bf16(af, bfr, acc[nt], 0, 0, 0);
        }
    }

    #pragma unroll
    for (int nt = 0; nt < 4; nt++) {
        int col = h * DH + nt * 16 + l16;
        #pragma unroll
        for (int r = 0; r < 4; r++) {
            int grow = m0 + wave * 16 + quad * 4 + r;
            attn[(size_t)grow * DM + col] = f2b(acc[nt][r]);
        }
    }
}

// ---------------- launch ------------------------------------------------------

extern "C" void kernel_launch(void* const* d_in, const int* in_sizes, int n_in,
                              void* d_out, int out_size, void* d_ws, size_t ws_size,
                              hipStream_t stream)
{
    const float* x  = (const float*)d_in[0];
    const float* Wq = (const float*)d_in[1];
    const float* bq = (const float*)d_in[2];
    const float* Wk = (const float*)d_in[3];
    const float* bk = (const float*)d_in[4];
    const float* Wv = (const float*)d_in[5];
    const float* bv = (const float*)d_in[6];
    const float* Wo = (const float*)d_in[7];
    const float* bo = (const float*)d_in[8];

    char* ws = (char*)d_ws;
    unsigned short* xb    = (unsigned short*)(ws);                              // 8 MB
    unsigned short* WqkvT = (unsigned short*)(ws + (size_t)8  * 1024 * 1024);   // 6 MB
    unsigned short* WoT   = (unsigned short*)(ws + (size_t)14 * 1024 * 1024);   // 2 MB
    float*          biasq = (float*)         (ws + (size_t)16 * 1024 * 1024);   // 12 KB
    unsigned short* QKV   = (unsigned short*)(ws + (size_t)17 * 1024 * 1024);   // 24 MB
    float*          KtV   = (float*)         (ws + (size_t)41 * 1024 * 1024);   // 512 KB
    unsigned short* attn  = xb;  // xb dead after QKV GEMM

    setup_kernel<<<6284, 256, 0, stream>>>(x, Wq, Wk, Wv, Wo, bq, bk, bv,
                                           xb, WqkvT, WoT, biasq, KtV);

    gemm_tn_kernel<128, true><<<dim3(NQKV / 128, M_ / 128), 256, 0, stream>>>(
        xb, WqkvT, biasq, QKV, M_, NQKV, DM);

    ktv_mfma_kernel<<<dim3(B_ * NH, 16), 256, 0, stream>>>(QKV, KtV);
    qktv_mfma_kernel<<<dim3(B_ * NH, L_ / 64), 256, 0, stream>>>(QKV, KtV, attn);

    gemm_tn_kernel<64, false><<<dim3(DM / 64, M_ / 128), 256, 0, stream>>>(
        attn, WoT, bo, d_out, M_, DM, DM);
}

// Round 5
// 164.764 us; speedup vs baseline: 2.6775x; 1.0171x over previous
//
#include <hip/hip_runtime.h>
#include <stdint.h>

#define B_ 2
#define L_ 2048
#define DM 1024
#define NH 16
#define DH 64
#define M_ (B_*L_)     // 4096
#define NQKV 3072

typedef short short8 __attribute__((ext_vector_type(8)));
typedef float f32x4 __attribute__((ext_vector_type(4)));

__device__ __forceinline__ unsigned short f2b(float f) {
    union { float f; unsigned int u; } v; v.f = f;
    unsigned int u = v.u;
    return (unsigned short)((u + 0x7fffu + ((u >> 16) & 1u)) >> 16);   // RNE
}

__device__ __forceinline__ void gld_lds16(const void* g, void* l) {
    __builtin_amdgcn_global_load_lds(
        (const __attribute__((address_space(1))) void*)g,
        (__attribute__((address_space(3))) void*)l, 16, 0, 0);
}

// ---------------- fused setup: x->bf16, 4x W transpose+cvt, bias pack, zero --
__global__ __launch_bounds__(256)
void setup_kernel(const float* __restrict__ x,
                  const float* __restrict__ Wq, const float* __restrict__ Wk,
                  const float* __restrict__ Wv, const float* __restrict__ Wo,
                  const float* __restrict__ bq, const float* __restrict__ bk,
                  const float* __restrict__ bv,
                  unsigned short* __restrict__ xb, unsigned short* __restrict__ WqkvT,
                  unsigned short* __restrict__ WoT, float* __restrict__ biasq,
                  float* __restrict__ KtV)
{
    __shared__ float tile[32][33];
    const int bid = blockIdx.x;
    const int t = threadIdx.x;

    if (bid < 2048) {
        int i = (bid * 256 + t) * 8;
        float4 a0 = *(const float4*)(x + i);
        float4 a1 = *(const float4*)(x + i + 4);
        uint4 p;
        p.x = (unsigned)f2b(a0.x) | ((unsigned)f2b(a0.y) << 16);
        p.y = (unsigned)f2b(a0.z) | ((unsigned)f2b(a0.w) << 16);
        p.z = (unsigned)f2b(a1.x) | ((unsigned)f2b(a1.y) << 16);
        p.w = (unsigned)f2b(a1.z) | ((unsigned)f2b(a1.w) << 16);
        *(uint4*)(xb + i) = p;
    } else if (bid < 2048 + 4096) {
        int wb = bid - 2048;
        int wi = wb >> 10;                // 0=Wq 1=Wk 2=Wv 3=Wo
        int tid = wb & 1023;
        const float* W = (wi == 0) ? Wq : (wi == 1) ? Wk : (wi == 2) ? Wv : Wo;
        unsigned short* dst = (wi < 3) ? (WqkvT + (size_t)wi * 1024 * 1024) : WoT;
        int n0 = (tid & 31) * 32, k0 = (tid >> 5) * 32;
        int r = t >> 3, c4 = (t & 7) << 2;
        float4 v = *(const float4*)(W + (size_t)(k0 + r) * DM + n0 + c4);
        tile[r][c4+0] = v.x; tile[r][c4+1] = v.y; tile[r][c4+2] = v.z; tile[r][c4+3] = v.w;
        __syncthreads();
        uint2 o;
        o.x = (unsigned)f2b(tile[c4+0][r]) | ((unsigned)f2b(tile[c4+1][r]) << 16);
        o.y = (unsigned)f2b(tile[c4+2][r]) | ((unsigned)f2b(tile[c4+3][r]) << 16);
        *(uint2*)(dst + (size_t)(n0 + r) * DM + k0 + c4) = o;
    } else if (bid < 2048 + 4096 + 12) {
        int i = (bid - 6144) * 256 + t;   // 0..3071
        float v = (i < 1024) ? bq[i] : (i < 2048 ? bk[i - 1024] : bv[i - 2048]);
        biasq[i] = v;
    } else {
        int i = ((bid - 6156) * 256 + t) * 4;  // zero KtV: 131072 floats
        float4 z; z.x = z.y = z.z = z.w = 0.f;
        *(float4*)(KtV + i) = z;
    }
}

// ---------------- 128xBN GEMM, BK=32 (proven round-3 structure) --------------
// Packed LDS [row][4 slots of 16B], slot s holds k-chunk s ^ ((row>>1)&3):
// frag ds_read_b128 are exactly 2-way bank-aliased (free, m136); staging
// satisfies global_load_lds wave-uniform base + lane*16.
// BATCHED_B: Bt has a separate 1024x1024 matrix per 2048-row batch of A.
template<int BN, bool OUT_BF16, bool BATCHED_B>
__global__ __launch_bounds__(256)
void gemm_tn_kernel(const unsigned short* __restrict__ A, int lda,
                    const unsigned short* __restrict__ Bt,
                    const float* __restrict__ bias,
                    void* __restrict__ C,
                    int M, int N, int K)
{
    constexpr int BM = 128;
    constexpr int MI = (BN == 128) ? 4 : 2;
    constexpr int MJ = 4;
    __shared__ __align__(16) unsigned short As[BM * 32];
    __shared__ __align__(16) unsigned short Bs[BN * 32];

    const int t = threadIdx.x;
    const int w = t >> 6, lane = t & 63;
    const int quad = lane >> 4, l16 = lane & 15;
    const int wm = (BN == 128) ? (w >> 1) : w;
    const int wn = (BN == 128) ? (w & 1) : 0;
    const int m0 = blockIdx.y * BM, n0 = blockIdx.x * BN;

    if constexpr (BATCHED_B) Bt += (size_t)(m0 >> 11) * 1024 * 1024;

    f32x4 acc[MI][MJ];
    #pragma unroll
    for (int i = 0; i < MI; i++)
        #pragma unroll
        for (int j = 0; j < MJ; j++)
            #pragma unroll
            for (int r = 0; r < 4; r++) acc[i][j][r] = 0.f;

    const int srow = t >> 2;        // 0..63
    const int schunk = t & 3;

    for (int kk = 0; kk < K; kk += 32) {
        #pragma unroll
        for (int p = 0; p < 2; p++) {               // A: 128 rows x 4 chunks
            int row = p * 64 + srow;
            int g = schunk ^ ((row >> 1) & 3);
            gld_lds16(A + (size_t)(m0 + row) * lda + kk + g * 8,
                      (char*)As + p * 4096 + w * 1024);
        }
        #pragma unroll
        for (int p = 0; p < BN / 64; p++) {         // B: BN rows x 4 chunks
            int row = p * 64 + srow;
            int g = schunk ^ ((row >> 1) & 3);
            gld_lds16(Bt + (size_t)(n0 + row) * K + kk + g * 8,
                      (char*)Bs + p * 4096 + w * 1024);
        }
        __syncthreads();

        short8 afr[MI], bfr[MJ];
        #pragma unroll
        for (int i = 0; i < MI; i++) {
            int am = wm * (MI * 16) + i * 16 + l16;
            afr[i] = *(const short8*)((const char*)As + am * 64 + ((quad ^ ((am >> 1) & 3)) << 4));
        }
        #pragma unroll
        for (int j = 0; j < MJ; j++) {
            int bn = wn * 64 + j * 16 + l16;
            bfr[j] = *(const short8*)((const char*)Bs + bn * 64 + ((quad ^ ((bn >> 1) & 3)) << 4));
        }
        #pragma unroll
        for (int i = 0; i < MI; i++)
            #pragma unroll
            for (int j = 0; j < MJ; j++)
                acc[i][j] = __builtin_amdgcn_mfma_f32_16x16x32_bf16(afr[i], bfr[j], acc[i][j], 0, 0, 0);
        __syncthreads();
    }

    #pragma unroll
    for (int j = 0; j < MJ; j++) {
        int col = n0 + wn * 64 + j * 16 + l16;
        float bv = bias[col];
        #pragma unroll
        for (int i = 0; i < MI; i++) {
            #pragma unroll
            for (int r = 0; r < 4; r++) {
                int row = m0 + wm * (MI * 16) + i * 16 + quad * 4 + r;
                float v = acc[i][j][r] + bv;
                if constexpr (OUT_BF16)
                    ((unsigned short*)C)[(size_t)row * N + col] = f2b(v);
                else
                    ((float*)C)[(size_t)row * N + col] = v;
            }
        }
    }
}

// ---------------- linear attention collapse ----------------------------------

// KtV[bh][d1][d2] += 0.125 * sum_{l in 128-chunk} K[.][d1]*V[.][d2]; split-K atomics
__global__ __launch_bounds__(256)
void ktv_mfma_kernel(const unsigned short* __restrict__ QKV, float* __restrict__ KtV)
{
    __shared__ __align__(16) unsigned short Ksl[64][40];  // [d1][l]
    __shared__ __align__(16) unsigned short Vsl[64][40];  // [d2][l]

    const int bh = blockIdx.x, chunk = blockIdx.y;
    const int b = bh >> 4, h = bh & 15;
    const int t = threadIdx.x;
    const int wave = t >> 6, lane = t & 63;
    const int quad = lane >> 4, l16 = lane & 15;
    const int lrow = t >> 3, c0 = (t & 7) << 3;

    f32x4 acc[4];
    #pragma unroll
    for (int i = 0; i < 4; i++)
        #pragma unroll
        for (int r = 0; r < 4; r++) acc[i][r] = 0.f;

    const size_t base0 = ((size_t)(b * L_ + chunk * 128)) * NQKV + (size_t)h * DH;
    for (int kk = 0; kk < 128; kk += 32) {
        size_t rb = base0 + (size_t)(kk + lrow) * NQKV + c0;
        uint4 kp = *(const uint4*)(QKV + rb + 1024);
        uint4 vp = *(const uint4*)(QKV + rb + 2048);
        Ksl[c0+0][lrow] = (unsigned short)(kp.x & 0xffff);
        Ksl[c0+1][lrow] = (unsigned short)(kp.x >> 16);
        Ksl[c0+2][lrow] = (unsigned short)(kp.y & 0xffff);
        Ksl[c0+3][lrow] = (unsigned short)(kp.y >> 16);
        Ksl[c0+4][lrow] = (unsigned short)(kp.z & 0xffff);
        Ksl[c0+5][lrow] = (unsigned short)(kp.z >> 16);
        Ksl[c0+6][lrow] = (unsigned short)(kp.w & 0xffff);
        Ksl[c0+7][lrow] = (unsigned short)(kp.w >> 16);
        Vsl[c0+0][lrow] = (unsigned short)(vp.x & 0xffff);
        Vsl[c0+1][lrow] = (unsigned short)(vp.x >> 16);
        Vsl[c0+2][lrow] = (unsigned short)(vp.y & 0xffff);
        Vsl[c0+3][lrow] = (unsigned short)(vp.y >> 16);
        Vsl[c0+4][lrow] = (unsigned short)(vp.z & 0xffff);
        Vsl[c0+5][lrow] = (unsigned short)(vp.z >> 16);
        Vsl[c0+6][lrow] = (unsigned short)(vp.w & 0xffff);
        Vsl[c0+7][lrow] = (unsigned short)(vp.w >> 16);
        __syncthreads();

        short8 af = *(const short8*)&Ksl[wave * 16 + l16][quad * 8];
        #pragma unroll
        for (int nt = 0; nt < 4; nt++) {
            short8 bfr = *(const short8*)&Vsl[nt * 16 + l16][quad * 8];
            acc[nt] = __builtin_amdgcn_mfma_f32_16x16x32_bf16(af, bfr, acc[nt], 0, 0, 0);
        }
        __syncthreads();
    }

    float* dst0 = KtV + (size_t)bh * 64 * 64;
    #pragma unroll
    for (int nt = 0; nt < 4; nt++) {
        int col = nt * 16 + l16;
        #pragma unroll
        for (int r = 0; r < 4; r++) {
            int row = wave * 16 + quad * 4 + r;
            atomicAdd(dst0 + row * 64 + col, acc[nt][r] * 0.125f);
        }
    }
}

// ZT[b][n][h*64+d1] = sum_d2 KtV[bh][d1][d2] * Wo[h*64+d2][n]
//   computed as C[n][d1] = sum_d2 WoT[n][h*64+d2] * KtV[bh][d1][d2]
// grid (32 bh, 16 n-tiles of 64)
__global__ __launch_bounds__(256)
void zmat_kernel(const unsigned short* __restrict__ WoT, const float* __restrict__ KtV,
                 unsigned short* __restrict__ ZT)
{
    __shared__ __align__(16) unsigned short Asl[64][72];  // [n][d2]
    __shared__ __align__(16) unsigned short Bsl[64][72];  // [d1][d2]

    const int bh = blockIdx.x, nt0 = blockIdx.y;
    const int b = bh >> 4, h = bh & 15;
    const int t = threadIdx.x;
    const int wave = t >> 6, lane = t & 63;
    const int quad = lane >> 4, l16 = lane & 15;
    const int n0 = nt0 * 64;
    const int row = t >> 2, c0 = (t & 3) << 4;

    const unsigned short* ap = WoT + (size_t)(n0 + row) * DM + h * DH + c0;
    *(uint4*)&Asl[row][c0]     = *(const uint4*)ap;
    *(uint4*)&Asl[row][c0 + 8] = *(const uint4*)(ap + 8);

    const float* kp = KtV + ((size_t)bh * 64 + row) * 64 + c0;
    #pragma unroll
    for (int j = 0; j < 16; j++) Bsl[row][c0 + j] = f2b(kp[j]);
    __syncthreads();

    f32x4 acc[4];
    #pragma unroll
    for (int i = 0; i < 4; i++)
        #pragma unroll
        for (int r = 0; r < 4; r++) acc[i][r] = 0.f;

    #pragma unroll
    for (int ks = 0; ks < 2; ks++) {
        short8 af = *(const short8*)&Asl[wave * 16 + l16][ks * 32 + quad * 8];
        #pragma unroll
        for (int nt = 0; nt < 4; nt++) {
            short8 bfr = *(const short8*)&Bsl[nt * 16 + l16][ks * 32 + quad * 8];
            acc[nt] = __builtin_amdgcn_mfma_f32_16x16x32_bf16(af, bfr, acc[nt], 0, 0, 0);
        }
    }

    unsigned short* zb = ZT + (size_t)b * 1024 * 1024 + (size_t)h * DH;
    #pragma unroll
    for (int nt = 0; nt < 4; nt++) {
        int col = nt * 16 + l16;     // d1
        #pragma unroll
        for (int r = 0; r < 4; r++) {
            int zr = n0 + wave * 16 + quad * 4 + r;   // n
            zb[(size_t)zr * 1024 + col] = f2b(acc[nt][r]);
        }
    }
}

// ---------------- launch ------------------------------------------------------

extern "C" void kernel_launch(void* const* d_in, const int* in_sizes, int n_in,
                              void* d_out, int out_size, void* d_ws, size_t ws_size,
                              hipStream_t stream)
{
    const float* x  = (const float*)d_in[0];
    const float* Wq = (const float*)d_in[1];
    const float* bq = (const float*)d_in[2];
    const float* Wk = (const float*)d_in[3];
    const float* bk = (const float*)d_in[4];
    const float* Wv = (const float*)d_in[5];
    const float* bv = (const float*)d_in[6];
    const float* Wo = (const float*)d_in[7];
    const float* bo = (const float*)d_in[8];

    char* ws = (char*)d_ws;
    unsigned short* xb    = (unsigned short*)(ws);                              // 8 MB
    unsigned short* WqkvT = (unsigned short*)(ws + (size_t)8  * 1024 * 1024);   // 6 MB
    unsigned short* WoT   = (unsigned short*)(ws + (size_t)14 * 1024 * 1024);   // 2 MB
    float*          biasq = (float*)         (ws + (size_t)16 * 1024 * 1024);   // 12 KB
    unsigned short* QKV   = (unsigned short*)(ws + (size_t)17 * 1024 * 1024);   // 24 MB
    float*          KtV   = (float*)         (ws + (size_t)41 * 1024 * 1024);   // 512 KB
    unsigned short* ZT    = xb;   // 4 MB, aliases xb (dead after QKV GEMM)

    setup_kernel<<<6284, 256, 0, stream>>>(x, Wq, Wk, Wv, Wo, bq, bk, bv,
                                           xb, WqkvT, WoT, biasq, KtV);

    // QKV projection [4096 x 3072 x 1024]
    gemm_tn_kernel<128, true, false><<<dim3(NQKV / 128, M_ / 128), 256, 0, stream>>>(
        xb, DM, WqkvT, biasq, QKV, M_, NQKV, DM);

    // K^T V  (32 bh x 16 L-chunks, split-K atomics)
    ktv_mfma_kernel<<<dim3(B_ * NH, 16), 256, 0, stream>>>(QKV, KtV);

    // ZT[b] = per-head KtV @ Wo   (tiny)
    zmat_kernel<<<dim3(B_ * NH, 16), 256, 0, stream>>>(WoT, KtV, ZT);

    // out = Q @ ZT[b] + bo   [2 x (2048 x 1024 x 1024)], Q read from QKV
    gemm_tn_kernel<64, false, true><<<dim3(DM / 64, M_ / 128), 256, 0, stream>>>(
        QKV, NQKV, ZT, bo, d_out, M_, DM, DM);
}

// Round 6
// 151.018 us; speedup vs baseline: 2.9212x; 1.0910x over previous
//
#include <hip/hip_runtime.h>
#include <stdint.h>

#define B_ 2
#define L_ 2048
#define DM 1024
#define NH 16
#define DH 64
#define M_ (B_*L_)     // 4096
#define NQKV 3072

typedef short short8 __attribute__((ext_vector_type(8)));
typedef float f32x4 __attribute__((ext_vector_type(4)));

__device__ __forceinline__ unsigned short f2b(float f) {
    union { float f; unsigned int u; } v; v.f = f;
    unsigned int u = v.u;
    return (unsigned short)((u + 0x7fffu + ((u >> 16) & 1u)) >> 16);   // RNE
}

__device__ __forceinline__ void gld_lds16(const void* g, void* l) {
    __builtin_amdgcn_global_load_lds(
        (const __attribute__((address_space(1))) void*)g,
        (__attribute__((address_space(3))) void*)l, 16, 0, 0);
}

// ---------------- fused setup ------------------------------------------------
// WqkvT row packing: rows 0..1023 = Wq^T; rows 1024 + h*128 + {0..63} = Wk^T
// head h (x0.125 folded, exact in bf16); +{64..127} = Wv^T head h.
__global__ __launch_bounds__(256)
void setup_kernel(const float* __restrict__ x,
                  const float* __restrict__ Wq, const float* __restrict__ Wk,
                  const float* __restrict__ Wv, const float* __restrict__ Wo,
                  const float* __restrict__ bq, const float* __restrict__ bk,
                  const float* __restrict__ bv,
                  unsigned short* __restrict__ xb, unsigned short* __restrict__ WqkvT,
                  unsigned short* __restrict__ WoT, float* __restrict__ biasq,
                  float* __restrict__ KtV)
{
    __shared__ float tile[32][33];
    const int bid = blockIdx.x;
    const int t = threadIdx.x;

    if (bid < 2048) {
        int i = (bid * 256 + t) * 8;
        float4 a0 = *(const float4*)(x + i);
        float4 a1 = *(const float4*)(x + i + 4);
        uint4 p;
        p.x = (unsigned)f2b(a0.x) | ((unsigned)f2b(a0.y) << 16);
        p.y = (unsigned)f2b(a0.z) | ((unsigned)f2b(a0.w) << 16);
        p.z = (unsigned)f2b(a1.x) | ((unsigned)f2b(a1.y) << 16);
        p.w = (unsigned)f2b(a1.z) | ((unsigned)f2b(a1.w) << 16);
        *(uint4*)(xb + i) = p;
    } else if (bid < 2048 + 4096) {
        int wb = bid - 2048;
        int wi = wb >> 10;                // 0=Wq 1=Wk 2=Wv 3=Wo
        int tid = wb & 1023;
        const float* W = (wi == 0) ? Wq : (wi == 1) ? Wk : (wi == 2) ? Wv : Wo;
        float s = (wi == 1) ? 0.125f : 1.0f;
        int n0 = (tid & 31) * 32, k0 = (tid >> 5) * 32;
        int r = t >> 3, c4 = (t & 7) << 2;
        float4 v = *(const float4*)(W + (size_t)(k0 + r) * DM + n0 + c4);
        tile[r][c4+0] = v.x; tile[r][c4+1] = v.y; tile[r][c4+2] = v.z; tile[r][c4+3] = v.w;
        __syncthreads();
        uint2 o;
        o.x = (unsigned)f2b(tile[c4+0][r]*s) | ((unsigned)f2b(tile[c4+1][r]*s) << 16);
        o.y = (unsigned)f2b(tile[c4+2][r]*s) | ((unsigned)f2b(tile[c4+3][r]*s) << 16);
        int f = n0 + r;                   // output feature
        size_t drow;
        unsigned short* dst;
        if (wi == 0)      { dst = WqkvT; drow = f; }
        else if (wi == 1) { dst = WqkvT; drow = 1024 + (f >> 6) * 128 + (f & 63); }
        else if (wi == 2) { dst = WqkvT; drow = 1024 + (f >> 6) * 128 + 64 + (f & 63); }
        else              { dst = WoT;   drow = f; }
        *(uint2*)(dst + drow * DM + k0 + c4) = o;
    } else if (bid < 2048 + 4096 + 12) {
        int n = (bid - 6144) * 256 + t;   // 0..3071
        float v;
        if (n < 1024) v = bq[n];
        else {
            int kv = (n - 1024) >> 7, r = (n - 1024) & 127;
            v = (r < 64) ? 0.125f * bk[kv * 64 + r] : bv[kv * 64 + (r - 64)];
        }
        biasq[n] = v;
    } else {
        int i = ((bid - 6156) * 256 + t) * 4;  // zero KtV: 131072 floats
        float4 z; z.x = z.y = z.z = z.w = 0.f;
        *(float4*)(KtV + i) = z;
    }
}

// ---------------- fused QKV projection + K^T V epilogue ----------------------
// grid (24 n-tiles, 32 m-tiles). nt<8: Q block -> Qb[4096][1024] bf16.
// nt>=8: head h=nt-8; K_h/V_h stay in regs, round-trip LDS transposed,
// 16 MFMAs/wave compute the 64x64x128L partial K^T V, atomicAdd into KtV.
__global__ __launch_bounds__(256)
void qkv_fused_kernel(const unsigned short* __restrict__ A,
                      const unsigned short* __restrict__ Bt,
                      const float* __restrict__ biasq,
                      unsigned short* __restrict__ Qb,
                      float* __restrict__ KtV)
{
    // K-loop uses first 16 KB as As/Bs; epilogue reuses all 34816 B as Xt[128][136]
    __shared__ __align__(16) char smem[34816];
    unsigned short* As = (unsigned short*)smem;
    unsigned short* Bs = (unsigned short*)(smem + 8192);

    const int t = threadIdx.x;
    const int w = t >> 6, lane = t & 63;
    const int quad = lane >> 4, l16 = lane & 15;
    const int wm = w >> 1, wn = w & 1;
    const int m0 = blockIdx.y * 128, n0 = blockIdx.x * 128;

    f32x4 acc[4][4];
    #pragma unroll
    for (int i = 0; i < 4; i++)
        #pragma unroll
        for (int j = 0; j < 4; j++)
            #pragma unroll
            for (int r = 0; r < 4; r++) acc[i][j][r] = 0.f;

    const int srow = t >> 2;
    const int schunk = t & 3;

    for (int kk = 0; kk < DM; kk += 32) {
        #pragma unroll
        for (int p = 0; p < 2; p++) {
            int row = p * 64 + srow;
            int g = schunk ^ ((row >> 1) & 3);
            gld_lds16(A  + (size_t)(m0 + row) * DM + kk + g * 8,
                      (char*)As + p * 4096 + w * 1024);
            gld_lds16(Bt + (size_t)(n0 + row) * DM + kk + g * 8,
                      (char*)Bs + p * 4096 + w * 1024);
        }
        __syncthreads();

        short8 afr[4], bfr[4];
        #pragma unroll
        for (int i = 0; i < 4; i++) {
            int am = wm * 64 + i * 16 + l16;
            afr[i] = *(const short8*)((const char*)As + am * 64 + ((quad ^ ((am >> 1) & 3)) << 4));
            int bn = wn * 64 + i * 16 + l16;
            bfr[i] = *(const short8*)((const char*)Bs + bn * 64 + ((quad ^ ((bn >> 1) & 3)) << 4));
        }
        #pragma unroll
        for (int i = 0; i < 4; i++)
            #pragma unroll
            for (int j = 0; j < 4; j++)
                acc[i][j] = __builtin_amdgcn_mfma_f32_16x16x32_bf16(afr[i], bfr[j], acc[i][j], 0, 0, 0);
        __syncthreads();   // also guards the epilogue's smem reuse
    }

    // bias
    #pragma unroll
    for (int j = 0; j < 4; j++) {
        float bv = biasq[n0 + wn * 64 + j * 16 + l16];
        #pragma unroll
        for (int i = 0; i < 4; i++)
            #pragma unroll
            for (int r = 0; r < 4; r++) acc[i][j][r] += bv;
    }

    if (blockIdx.x < 8) {
        // Q block: store to compact Q buffer
        #pragma unroll
        for (int j = 0; j < 4; j++) {
            int col = n0 + wn * 64 + j * 16 + l16;
            #pragma unroll
            for (int i = 0; i < 4; i++) {
                #pragma unroll
                for (int r = 0; r < 4; r++) {
                    int row = m0 + wm * 64 + i * 16 + quad * 4 + r;
                    Qb[(size_t)row * DM + col] = f2b(acc[i][j][r]);
                }
            }
        }
        return;
    }

    // ---- KV block: head h; cols 0..63 of tile = K_h, 64..127 = V_h ----
    const int h  = blockIdx.x - 8;
    const int bh = (m0 >> 11) * NH + h;
    unsigned short (*Xt)[136] = (unsigned short (*)[136])smem;   // [c][l]

    // transposed store: Xt[c][l]; 4 consecutive l per acc reg quad (8B stores)
    #pragma unroll
    for (int j = 0; j < 4; j++) {
        int c = wn * 64 + j * 16 + l16;
        #pragma unroll
        for (int i = 0; i < 4; i++) {
            int l0 = wm * 64 + i * 16 + quad * 4;
            uint2 o;
            o.x = (unsigned)f2b(acc[i][j][0]) | ((unsigned)f2b(acc[i][j][1]) << 16);
            o.y = (unsigned)f2b(acc[i][j][2]) | ((unsigned)f2b(acc[i][j][3]) << 16);
            *(uint2*)&Xt[c][l0] = o;
        }
    }
    __syncthreads();

    // K^T V over this 128-L chunk: wave w computes d1 in [w*16, w*16+16)
    f32x4 kacc[4];
    #pragma unroll
    for (int j = 0; j < 4; j++)
        #pragma unroll
        for (int r = 0; r < 4; r++) kacc[j][r] = 0.f;

    #pragma unroll
    for (int ks = 0; ks < 4; ks++) {
        short8 af = *(const short8*)&Xt[w * 16 + l16][ks * 32 + quad * 8];
        #pragma unroll
        for (int j = 0; j < 4; j++) {
            short8 bfr = *(const short8*)&Xt[64 + j * 16 + l16][ks * 32 + quad * 8];
            kacc[j] = __builtin_amdgcn_mfma_f32_16x16x32_bf16(af, bfr, kacc[j], 0, 0, 0);
        }
    }

    float* dst = KtV + (size_t)bh * 64 * 64;
    #pragma unroll
    for (int j = 0; j < 4; j++) {
        int col = j * 16 + l16;
        #pragma unroll
        for (int r = 0; r < 4; r++) {
            int row = w * 16 + quad * 4 + r;
            atomicAdd(dst + row * 64 + col, kacc[j][r]);
        }
    }
}

// ---------------- ZT[b][n][h*64+d1] = sum_d2 KtV[bh][d1][d2]*WoT[n][h*64+d2] --
__global__ __launch_bounds__(256)
void zmat_kernel(const unsigned short* __restrict__ WoT, const float* __restrict__ KtV,
                 unsigned short* __restrict__ ZT)
{
    __shared__ __align__(16) unsigned short Asl[64][72];  // [n][d2]
    __shared__ __align__(16) unsigned short Bsl[64][72];  // [d1][d2]

    const int bh = blockIdx.x, nt0 = blockIdx.y;
    const int b = bh >> 4, h = bh & 15;
    const int t = threadIdx.x;
    const int wave = t >> 6, lane = t & 63;
    const int quad = lane >> 4, l16 = lane & 15;
    const int n0 = nt0 * 64;
    const int row = t >> 2, c0 = (t & 3) << 4;

    const unsigned short* ap = WoT + (size_t)(n0 + row) * DM + h * DH + c0;
    *(uint4*)&Asl[row][c0]     = *(const uint4*)ap;
    *(uint4*)&Asl[row][c0 + 8] = *(const uint4*)(ap + 8);

    const float* kp = KtV + ((size_t)bh * 64 + row) * 64 + c0;
    #pragma unroll
    for (int j = 0; j < 16; j++) Bsl[row][c0 + j] = f2b(kp[j]);
    __syncthreads();

    f32x4 acc[4];
    #pragma unroll
    for (int i = 0; i < 4; i++)
        #pragma unroll
        for (int r = 0; r < 4; r++) acc[i][r] = 0.f;

    #pragma unroll
    for (int ks = 0; ks < 2; ks++) {
        short8 af = *(const short8*)&Asl[wave * 16 + l16][ks * 32 + quad * 8];
        #pragma unroll
        for (int nt = 0; nt < 4; nt++) {
            short8 bfr = *(const short8*)&Bsl[nt * 16 + l16][ks * 32 + quad * 8];
            acc[nt] = __builtin_amdgcn_mfma_f32_16x16x32_bf16(af, bfr, acc[nt], 0, 0, 0);
        }
    }

    unsigned short* zb = ZT + (size_t)b * 1024 * 1024 + (size_t)h * DH;
    #pragma unroll
    for (int nt = 0; nt < 4; nt++) {
        int col = nt * 16 + l16;     // d1
        #pragma unroll
        for (int r = 0; r < 4; r++) {
            int zr = n0 + wave * 16 + quad * 4 + r;   // n
            zb[(size_t)zr * 1024 + col] = f2b(acc[nt][r]);
        }
    }
}

// ---------------- final GEMM: out = Q @ ZT[b] + bo ---------------------------
template<int BN, bool OUT_BF16, bool BATCHED_B>
__global__ __launch_bounds__(256)
void gemm_tn_kernel(const unsigned short* __restrict__ A, int lda,
                    const unsigned short* __restrict__ Bt,
                    const float* __restrict__ bias,
                    void* __restrict__ C,
                    int M, int N, int K)
{
    constexpr int BM = 128;
    constexpr int MI = (BN == 128) ? 4 : 2;
    constexpr int MJ = 4;
    __shared__ __align__(16) unsigned short As[BM * 32];
    __shared__ __align__(16) unsigned short Bs[BN * 32];

    const int t = threadIdx.x;
    const int w = t >> 6, lane = t & 63;
    const int quad = lane >> 4, l16 = lane & 15;
    const int wm = (BN == 128) ? (w >> 1) : w;
    const int wn = (BN == 128) ? (w & 1) : 0;
    const int m0 = blockIdx.y * BM, n0 = blockIdx.x * BN;

    if constexpr (BATCHED_B) Bt += (size_t)(m0 >> 11) * 1024 * 1024;

    f32x4 acc[MI][MJ];
    #pragma unroll
    for (int i = 0; i < MI; i++)
        #pragma unroll
        for (int j = 0; j < MJ; j++)
            #pragma unroll
            for (int r = 0; r < 4; r++) acc[i][j][r] = 0.f;

    const int srow = t >> 2;
    const int schunk = t & 3;

    for (int kk = 0; kk < K; kk += 32) {
        #pragma unroll
        for (int p = 0; p < 2; p++) {
            int row = p * 64 + srow;
            int g = schunk ^ ((row >> 1) & 3);
            gld_lds16(A + (size_t)(m0 + row) * lda + kk + g * 8,
                      (char*)As + p * 4096 + w * 1024);
        }
        #pragma unroll
        for (int p = 0; p < BN / 64; p++) {
            int row = p * 64 + srow;
            int g = schunk ^ ((row >> 1) & 3);
            gld_lds16(Bt + (size_t)(n0 + row) * K + kk + g * 8,
                      (char*)Bs + p * 4096 + w * 1024);
        }
        __syncthreads();

        short8 afr[MI], bfr[MJ];
        #pragma unroll
        for (int i = 0; i < MI; i++) {
            int am = wm * (MI * 16) + i * 16 + l16;
            afr[i] = *(const short8*)((const char*)As + am * 64 + ((quad ^ ((am >> 1) & 3)) << 4));
        }
        #pragma unroll
        for (int j = 0; j < MJ; j++) {
            int bn = wn * 64 + j * 16 + l16;
            bfr[j] = *(const short8*)((const char*)Bs + bn * 64 + ((quad ^ ((bn >> 1) & 3)) << 4));
        }
        #pragma unroll
        for (int i = 0; i < MI; i++)
            #pragma unroll
            for (int j = 0; j < MJ; j++)
                acc[i][j] = __builtin_amdgcn_mfma_f32_16x16x32_bf16(afr[i], bfr[j], acc[i][j], 0, 0, 0);
        __syncthreads();
    }

    #pragma unroll
    for (int j = 0; j < MJ; j++) {
        int col = n0 + wn * 64 + j * 16 + l16;
        float bv = bias[col];
        #pragma unroll
        for (int i = 0; i < MI; i++) {
            #pragma unroll
            for (int r = 0; r < 4; r++) {
                int row = m0 + wm * (MI * 16) + i * 16 + quad * 4 + r;
                float v = acc[i][j][r] + bv;
                if constexpr (OUT_BF16)
                    ((unsigned short*)C)[(size_t)row * N + col] = f2b(v);
                else
                    ((float*)C)[(size_t)row * N + col] = v;
            }
        }
    }
}

// ---------------- launch ------------------------------------------------------

extern "C" void kernel_launch(void* const* d_in, const int* in_sizes, int n_in,
                              void* d_out, int out_size, void* d_ws, size_t ws_size,
                              hipStream_t stream)
{
    const float* x  = (const float*)d_in[0];
    const float* Wq = (const float*)d_in[1];
    const float* bq = (const float*)d_in[2];
    const float* Wk = (const float*)d_in[3];
    const float* bk = (const float*)d_in[4];
    const float* Wv = (const float*)d_in[5];
    const float* bv = (const float*)d_in[6];
    const float* Wo = (const float*)d_in[7];
    const float* bo = (const float*)d_in[8];

    char* ws = (char*)d_ws;
    unsigned short* xb    = (unsigned short*)(ws);                              // 8 MB
    unsigned short* WqkvT = (unsigned short*)(ws + (size_t)8  * 1024 * 1024);   // 6 MB
    unsigned short* WoT   = (unsigned short*)(ws + (size_t)14 * 1024 * 1024);   // 2 MB
    float*          biasq = (float*)         (ws + (size_t)16 * 1024 * 1024);   // 12 KB
    unsigned short* Qb    = (unsigned short*)(ws + (size_t)17 * 1024 * 1024);   // 8 MB
    unsigned short* ZT    = (unsigned short*)(ws + (size_t)25 * 1024 * 1024);   // 4 MB
    float*          KtV   = (float*)         (ws + (size_t)29 * 1024 * 1024);   // 512 KB

    setup_kernel<<<6284, 256, 0, stream>>>(x, Wq, Wk, Wv, Wo, bq, bk, bv,
                                           xb, WqkvT, WoT, biasq, KtV);

    // fused QKV projection + K^T V accumulation
    qkv_fused_kernel<<<dim3(NQKV / 128, M_ / 128), 256, 0, stream>>>(
        xb, WqkvT, biasq, Qb, KtV);

    // ZT[b] = per-head KtV @ Wo (scale already folded into K)
    zmat_kernel<<<dim3(B_ * NH, 16), 256, 0, stream>>>(WoT, KtV, ZT);

    // out = Q @ ZT[b] + bo
    gemm_tn_kernel<64, false, true><<<dim3(DM / 64, M_ / 128), 256, 0, stream>>>(
        Qb, DM, ZT, bo, d_out, M_, DM, DM);
}

// Round 7
// 147.036 us; speedup vs baseline: 3.0004x; 1.0271x over previous
//
#include <hip/hip_runtime.h>
#include <stdint.h>

#define B_ 2
#define L_ 2048
#define DM 1024
#define NH 16
#define DH 64
#define M_ (B_*L_)     // 4096
#define NQKV 3072

typedef short short8 __attribute__((ext_vector_type(8)));
typedef float f32x4 __attribute__((ext_vector_type(4)));

__device__ __forceinline__ unsigned short f2b(float f) {
    union { float f; unsigned int u; } v; v.f = f;
    unsigned int u = v.u;
    return (unsigned short)((u + 0x7fffu + ((u >> 16) & 1u)) >> 16);   // RNE
}

__device__ __forceinline__ void gld_lds16(const void* g, void* l) {
    __builtin_amdgcn_global_load_lds(
        (const __attribute__((address_space(1))) void*)g,
        (__attribute__((address_space(3))) void*)l, 16, 0, 0);
}

// ---------------- fused setup ------------------------------------------------
// WqkvT row packing: rows 0..1023 = Wq^T; rows 1024 + h*128 + {0..63} = Wk^T
// head h (x0.125 folded); +{64..127} = Wv^T head h.
__global__ __launch_bounds__(256)
void setup_kernel(const float* __restrict__ x,
                  const float* __restrict__ Wq, const float* __restrict__ Wk,
                  const float* __restrict__ Wv, const float* __restrict__ Wo,
                  const float* __restrict__ bq, const float* __restrict__ bk,
                  const float* __restrict__ bv,
                  unsigned short* __restrict__ xb, unsigned short* __restrict__ WqkvT,
                  unsigned short* __restrict__ WoT, float* __restrict__ biasq,
                  float* __restrict__ KtV)
{
    __shared__ float tile[32][33];
    const int bid = blockIdx.x;
    const int t = threadIdx.x;

    if (bid < 2048) {
        int i = (bid * 256 + t) * 8;
        float4 a0 = *(const float4*)(x + i);
        float4 a1 = *(const float4*)(x + i + 4);
        uint4 p;
        p.x = (unsigned)f2b(a0.x) | ((unsigned)f2b(a0.y) << 16);
        p.y = (unsigned)f2b(a0.z) | ((unsigned)f2b(a0.w) << 16);
        p.z = (unsigned)f2b(a1.x) | ((unsigned)f2b(a1.y) << 16);
        p.w = (unsigned)f2b(a1.z) | ((unsigned)f2b(a1.w) << 16);
        *(uint4*)(xb + i) = p;
    } else if (bid < 2048 + 4096) {
        int wb = bid - 2048;
        int wi = wb >> 10;                // 0=Wq 1=Wk 2=Wv 3=Wo
        int tid = wb & 1023;
        const float* W = (wi == 0) ? Wq : (wi == 1) ? Wk : (wi == 2) ? Wv : Wo;
        float s = (wi == 1) ? 0.125f : 1.0f;
        int n0 = (tid & 31) * 32, k0 = (tid >> 5) * 32;
        int r = t >> 3, c4 = (t & 7) << 2;
        float4 v = *(const float4*)(W + (size_t)(k0 + r) * DM + n0 + c4);
        tile[r][c4+0] = v.x; tile[r][c4+1] = v.y; tile[r][c4+2] = v.z; tile[r][c4+3] = v.w;
        __syncthreads();
        uint2 o;
        o.x = (unsigned)f2b(tile[c4+0][r]*s) | ((unsigned)f2b(tile[c4+1][r]*s) << 16);
        o.y = (unsigned)f2b(tile[c4+2][r]*s) | ((unsigned)f2b(tile[c4+3][r]*s) << 16);
        int f = n0 + r;
        size_t drow;
        unsigned short* dst;
        if (wi == 0)      { dst = WqkvT; drow = f; }
        else if (wi == 1) { dst = WqkvT; drow = 1024 + (f >> 6) * 128 + (f & 63); }
        else if (wi == 2) { dst = WqkvT; drow = 1024 + (f >> 6) * 128 + 64 + (f & 63); }
        else              { dst = WoT;   drow = f; }
        *(uint2*)(dst + drow * DM + k0 + c4) = o;
    } else if (bid < 2048 + 4096 + 12) {
        int n = (bid - 6144) * 256 + t;
        float v;
        if (n < 1024) v = bq[n];
        else {
            int kv = (n - 1024) >> 7, r = (n - 1024) & 127;
            v = (r < 64) ? 0.125f * bk[kv * 64 + r] : bv[kv * 64 + (r - 64)];
        }
        biasq[n] = v;
    } else {
        int i = ((bid - 6156) * 256 + t) * 4;
        float4 z; z.x = z.y = z.z = z.w = 0.f;
        *(float4*)(KtV + i) = z;
    }
}

// ---------------- fused QKV projection + K^T V epilogue ----------------------
// 1-D grid of 768, XCD-swizzled: xcd = bid&7 owns m-tiles [xcd*4, xcd*4+4)
// (1 MB A-slice hot in its private L2); n sweeps with m fastest so 4
// consecutive blocks share one B tile. nt<8 -> Q; nt>=8 -> head nt-8 K/V.
__global__ __launch_bounds__(256)
void qkv_fused_kernel(const unsigned short* __restrict__ A,
                      const unsigned short* __restrict__ Bt,
                      const float* __restrict__ biasq,
                      unsigned short* __restrict__ Qb,
                      float* __restrict__ KtV)
{
    __shared__ __align__(16) char smem[34816];
    unsigned short* As = (unsigned short*)smem;
    unsigned short* Bs = (unsigned short*)(smem + 8192);

    const int bid = blockIdx.x;
    const int xcd = bid & 7, local = bid >> 3;    // 96 blocks per XCD
    const int mt = xcd * 4 + (local & 3);         // 0..31
    const int nt = local >> 2;                    // 0..23
    const int m0 = mt * 128, n0 = nt * 128;

    const int t = threadIdx.x;
    const int w = t >> 6, lane = t & 63;
    const int quad = lane >> 4, l16 = lane & 15;
    const int wm = w >> 1, wn = w & 1;

    f32x4 acc[4][4];
    #pragma unroll
    for (int i = 0; i < 4; i++)
        #pragma unroll
        for (int j = 0; j < 4; j++)
            #pragma unroll
            for (int r = 0; r < 4; r++) acc[i][j][r] = 0.f;

    const int srow = t >> 2;
    const int schunk = t & 3;

    for (int kk = 0; kk < DM; kk += 32) {
        #pragma unroll
        for (int p = 0; p < 2; p++) {
            int row = p * 64 + srow;
            int g = schunk ^ ((row >> 1) & 3);
            gld_lds16(A  + (size_t)(m0 + row) * DM + kk + g * 8,
                      (char*)As + p * 4096 + w * 1024);
            gld_lds16(Bt + (size_t)(n0 + row) * DM + kk + g * 8,
                      (char*)Bs + p * 4096 + w * 1024);
        }
        __syncthreads();

        short8 afr[4], bfr[4];
        #pragma unroll
        for (int i = 0; i < 4; i++) {
            int am = wm * 64 + i * 16 + l16;
            afr[i] = *(const short8*)((const char*)As + am * 64 + ((quad ^ ((am >> 1) & 3)) << 4));
            int bn = wn * 64 + i * 16 + l16;
            bfr[i] = *(const short8*)((const char*)Bs + bn * 64 + ((quad ^ ((bn >> 1) & 3)) << 4));
        }
        #pragma unroll
        for (int i = 0; i < 4; i++)
            #pragma unroll
            for (int j = 0; j < 4; j++)
                acc[i][j] = __builtin_amdgcn_mfma_f32_16x16x32_bf16(afr[i], bfr[j], acc[i][j], 0, 0, 0);
        __syncthreads();
    }

    #pragma unroll
    for (int j = 0; j < 4; j++) {
        float bv = biasq[n0 + wn * 64 + j * 16 + l16];
        #pragma unroll
        for (int i = 0; i < 4; i++)
            #pragma unroll
            for (int r = 0; r < 4; r++) acc[i][j][r] += bv;
    }

    if (nt < 8) {
        #pragma unroll
        for (int j = 0; j < 4; j++) {
            int col = n0 + wn * 64 + j * 16 + l16;
            #pragma unroll
            for (int i = 0; i < 4; i++) {
                #pragma unroll
                for (int r = 0; r < 4; r++) {
                    int row = m0 + wm * 64 + i * 16 + quad * 4 + r;
                    Qb[(size_t)row * DM + col] = f2b(acc[i][j][r]);
                }
            }
        }
        return;
    }

    // ---- KV block: head h; tile cols 0..63 = K_h, 64..127 = V_h ----
    const int h  = nt - 8;
    const int bh = (m0 >> 11) * NH + h;
    unsigned short (*Xt)[136] = (unsigned short (*)[136])smem;   // [c][l]

    #pragma unroll
    for (int j = 0; j < 4; j++) {
        int c = wn * 64 + j * 16 + l16;
        #pragma unroll
        for (int i = 0; i < 4; i++) {
            int l0 = wm * 64 + i * 16 + quad * 4;
            uint2 o;
            o.x = (unsigned)f2b(acc[i][j][0]) | ((unsigned)f2b(acc[i][j][1]) << 16);
            o.y = (unsigned)f2b(acc[i][j][2]) | ((unsigned)f2b(acc[i][j][3]) << 16);
            *(uint2*)&Xt[c][l0] = o;
        }
    }
    __syncthreads();

    f32x4 kacc[4];
    #pragma unroll
    for (int j = 0; j < 4; j++)
        #pragma unroll
        for (int r = 0; r < 4; r++) kacc[j][r] = 0.f;

    #pragma unroll
    for (int ks = 0; ks < 4; ks++) {
        short8 af = *(const short8*)&Xt[w * 16 + l16][ks * 32 + quad * 8];
        #pragma unroll
        for (int j = 0; j < 4; j++) {
            short8 bfr = *(const short8*)&Xt[64 + j * 16 + l16][ks * 32 + quad * 8];
            kacc[j] = __builtin_amdgcn_mfma_f32_16x16x32_bf16(af, bfr, kacc[j], 0, 0, 0);
        }
    }

    float* dst = KtV + (size_t)bh * 64 * 64;
    #pragma unroll
    for (int j = 0; j < 4; j++) {
        int col = j * 16 + l16;
        #pragma unroll
        for (int r = 0; r < 4; r++) {
            int row = w * 16 + quad * 4 + r;
            atomicAdd(dst + row * 64 + col, kacc[j][r]);
        }
    }
}

// ---------------- ZT[b][n][h*64+d1] = sum_d2 KtV[bh][d1][d2]*WoT[n][h*64+d2] --
__global__ __launch_bounds__(256)
void zmat_kernel(const unsigned short* __restrict__ WoT, const float* __restrict__ KtV,
                 unsigned short* __restrict__ ZT)
{
    __shared__ __align__(16) unsigned short Asl[64][72];  // [n][d2]
    __shared__ __align__(16) unsigned short Bsl[64][72];  // [d1][d2]

    const int bh = blockIdx.x, nt0 = blockIdx.y;
    const int b = bh >> 4, h = bh & 15;
    const int t = threadIdx.x;
    const int wave = t >> 6, lane = t & 63;
    const int quad = lane >> 4, l16 = lane & 15;
    const int n0 = nt0 * 64;
    const int row = t >> 2, c0 = (t & 3) << 4;

    const unsigned short* ap = WoT + (size_t)(n0 + row) * DM + h * DH + c0;
    *(uint4*)&Asl[row][c0]     = *(const uint4*)ap;
    *(uint4*)&Asl[row][c0 + 8] = *(const uint4*)(ap + 8);

    const float* kp = KtV + ((size_t)bh * 64 + row) * 64 + c0;
    #pragma unroll
    for (int j = 0; j < 16; j++) Bsl[row][c0 + j] = f2b(kp[j]);
    __syncthreads();

    f32x4 acc[4];
    #pragma unroll
    for (int i = 0; i < 4; i++)
        #pragma unroll
        for (int r = 0; r < 4; r++) acc[i][r] = 0.f;

    #pragma unroll
    for (int ks = 0; ks < 2; ks++) {
        short8 af = *(const short8*)&Asl[wave * 16 + l16][ks * 32 + quad * 8];
        #pragma unroll
        for (int nt = 0; nt < 4; nt++) {
            short8 bfr = *(const short8*)&Bsl[nt * 16 + l16][ks * 32 + quad * 8];
            acc[nt] = __builtin_amdgcn_mfma_f32_16x16x32_bf16(af, bfr, acc[nt], 0, 0, 0);
        }
    }

    unsigned short* zb = ZT + (size_t)b * 1024 * 1024 + (size_t)h * DH;
    #pragma unroll
    for (int nt = 0; nt < 4; nt++) {
        int col = nt * 16 + l16;
        #pragma unroll
        for (int r = 0; r < 4; r++) {
            int zr = n0 + wave * 16 + quad * 4 + r;
            zb[(size_t)zr * 1024 + col] = f2b(acc[nt][r]);
        }
    }
}

// ---------------- final GEMM: out = Q @ ZT[b] + bo, XCD-swizzled -------------
// 1-D grid 512: xcd = bid&7 owns m-tiles [xcd*4, xcd*4+4) (1 MB Q slice in L2),
// n sweeps with m fastest.
__global__ __launch_bounds__(256)
void out_gemm_kernel(const unsigned short* __restrict__ A,
                     const unsigned short* __restrict__ Bt,
                     const float* __restrict__ bias,
                     float* __restrict__ C)
{
    constexpr int BN = 64, MI = 2, MJ = 4;
    __shared__ __align__(16) unsigned short As[128 * 32];
    __shared__ __align__(16) unsigned short Bs[BN * 32];

    const int bid = blockIdx.x;
    const int xcd = bid & 7, local = bid >> 3;   // 64 per XCD
    const int mt = xcd * 4 + (local & 3);        // 0..31
    const int nt = local >> 2;                   // 0..15
    const int m0 = mt * 128, n0 = nt * 64;

    const int t = threadIdx.x;
    const int w = t >> 6, lane = t & 63;
    const int quad = lane >> 4, l16 = lane & 15;

    const unsigned short* Btb = Bt + (size_t)(m0 >> 11) * 1024 * 1024;

    f32x4 acc[MI][MJ];
    #pragma unroll
    for (int i = 0; i < MI; i++)
        #pragma unroll
        for (int j = 0; j < MJ; j++)
            #pragma unroll
            for (int r = 0; r < 4; r++) acc[i][j][r] = 0.f;

    const int srow = t >> 2;
    const int schunk = t & 3;

    for (int kk = 0; kk < DM; kk += 32) {
        #pragma unroll
        for (int p = 0; p < 2; p++) {
            int row = p * 64 + srow;
            int g = schunk ^ ((row >> 1) & 3);
            gld_lds16(A + (size_t)(m0 + row) * DM + kk + g * 8,
                      (char*)As + p * 4096 + w * 1024);
        }
        {
            int row = srow;
            int g = schunk ^ ((row >> 1) & 3);
            gld_lds16(Btb + (size_t)(n0 + row) * DM + kk + g * 8,
                      (char*)Bs + w * 1024);
        }
        __syncthreads();

        short8 afr[MI], bfr[MJ];
        #pragma unroll
        for (int i = 0; i < MI; i++) {
            int am = w * 32 + i * 16 + l16;
            afr[i] = *(const short8*)((const char*)As + am * 64 + ((quad ^ ((am >> 1) & 3)) << 4));
        }
        #pragma unroll
        for (int j = 0; j < MJ; j++) {
            int bn = j * 16 + l16;
            bfr[j] = *(const short8*)((const char*)Bs + bn * 64 + ((quad ^ ((bn >> 1) & 3)) << 4));
        }
        #pragma unroll
        for (int i = 0; i < MI; i++)
            #pragma unroll
            for (int j = 0; j < MJ; j++)
                acc[i][j] = __builtin_amdgcn_mfma_f32_16x16x32_bf16(afr[i], bfr[j], acc[i][j], 0, 0, 0);
        __syncthreads();
    }

    #pragma unroll
    for (int j = 0; j < MJ; j++) {
        int col = n0 + j * 16 + l16;
        float bv = bias[col];
        #pragma unroll
        for (int i = 0; i < MI; i++) {
            #pragma unroll
            for (int r = 0; r < 4; r++) {
                int row = m0 + w * 32 + i * 16 + quad * 4 + r;
                C[(size_t)row * DM + col] = acc[i][j][r] + bv;
            }
        }
    }
}

// ---------------- launch ------------------------------------------------------

extern "C" void kernel_launch(void* const* d_in, const int* in_sizes, int n_in,
                              void* d_out, int out_size, void* d_ws, size_t ws_size,
                              hipStream_t stream)
{
    const float* x  = (const float*)d_in[0];
    const float* Wq = (const float*)d_in[1];
    const float* bq = (const float*)d_in[2];
    const float* Wk = (const float*)d_in[3];
    const float* bk = (const float*)d_in[4];
    const float* Wv = (const float*)d_in[5];
    const float* bv = (const float*)d_in[6];
    const float* Wo = (const float*)d_in[7];
    const float* bo = (const float*)d_in[8];

    char* ws = (char*)d_ws;
    unsigned short* xb    = (unsigned short*)(ws);                              // 8 MB
    unsigned short* WqkvT = (unsigned short*)(ws + (size_t)8  * 1024 * 1024);   // 6 MB
    unsigned short* WoT   = (unsigned short*)(ws + (size_t)14 * 1024 * 1024);   // 2 MB
    float*          biasq = (float*)         (ws + (size_t)16 * 1024 * 1024);   // 12 KB
    unsigned short* Qb    = (unsigned short*)(ws + (size_t)17 * 1024 * 1024);   // 8 MB
    unsigned short* ZT    = (unsigned short*)(ws + (size_t)25 * 1024 * 1024);   // 4 MB
    float*          KtV   = (float*)         (ws + (size_t)29 * 1024 * 1024);   // 512 KB

    setup_kernel<<<6284, 256, 0, stream>>>(x, Wq, Wk, Wv, Wo, bq, bk, bv,
                                           xb, WqkvT, WoT, biasq, KtV);

    qkv_fused_kernel<<<768, 256, 0, stream>>>(xb, WqkvT, biasq, Qb, KtV);

    zmat_kernel<<<dim3(B_ * NH, 16), 256, 0, stream>>>(WoT, KtV, ZT);

    out_gemm_kernel<<<512, 256, 0, stream>>>(Qb, ZT, bo, (float*)d_out);
}